// Round 12
// baseline (288.944 us; speedup 1.0000x reference)
//
#include <hip/hip_runtime.h>

static constexpr int NLr = 2048;    // ligand rows
static constexpr int NPr = 16384;   // protein rows
static constexpr int DIM = 256;     // feature dim
static constexpr int NB  = 32;      // batch count

typedef unsigned short bf16_t;
using bf16x8 = __attribute__((ext_vector_type(8))) short;
using f32x4  = __attribute__((ext_vector_type(4))) float;

__device__ inline float bf2f(bf16_t u){
  union { unsigned int i; float f; } c; c.i = ((unsigned int)u) << 16; return c.f;
}
__device__ inline bf16_t f2bf(float f){
  union { float f; unsigned int i; } c; c.f = f;
  unsigned int x = c.i;
  return (bf16_t)((x + 0x7fffu + ((x >> 16) & 1u)) >> 16);  // RNE
}
__device__ inline float wave_sum(float x){
  #pragma unroll
  for (int off = 32; off; off >>= 1) x += __shfl_xor(x, off, 64);
  return x;
}
__device__ inline bf16x8 ldfrag_f32(const float* p){
  float4 a = *reinterpret_cast<const float4*>(p);
  float4 b = *reinterpret_cast<const float4*>(p + 4);
  bf16x8 r;
  r[0]=(short)f2bf(a.x); r[1]=(short)f2bf(a.y); r[2]=(short)f2bf(a.z); r[3]=(short)f2bf(a.w);
  r[4]=(short)f2bf(b.x); r[5]=(short)f2bf(b.y); r[6]=(short)f2bf(b.z); r[7]=(short)f2bf(b.w);
  return r;
}
// fp32 -> (hi, lo) bf16 pair; str = element stride source
__device__ inline void hilo8(const float* p, bf16x8& hi, bf16x8& lo){
  #pragma unroll
  for (int i = 0; i < 8; i++){
    float v = p[i];
    bf16_t h = f2bf(v);
    hi[i] = (short)h;
    lo[i] = (short)f2bf(v - bf2f(h));
  }
}

// lig partials: O-partials in d_out tail (pro-out region, consumed before attn_pro)
static constexpr int OPART_OFF = 524288;   // floats; 1024 * 4096 ends at d_out end

// ---- batch block boundaries ----
__global__ void bounds_kernel(const int* __restrict__ lb, const int* __restrict__ pb,
                              int* __restrict__ ls, int* __restrict__ ps){
  int t = threadIdx.x;
  if (t <= NB){
    int lo = 0, hi = NLr;
    while (lo < hi){ int mid = (lo + hi) >> 1; if (lb[mid] < t) lo = mid + 1; else hi = mid; }
    ls[t] = lo;
    lo = 0; hi = NPr;
    while (lo < hi){ int mid = (lo + hi) >> 1; if (pb[mid] < t) lo = mid + 1; else hi = mid; }
    ps[t] = lo;
  }
}

// ---- 4 weight products in one launch: z<2 -> A^T B ; z>=2 -> A B ----
__global__ __launch_bounds__(256) void wprod4(
    const float* __restrict__ Wq_lig, const float* __restrict__ Wk_pro,
    const float* __restrict__ Wk_lig, const float* __restrict__ Wq_pro,
    const float* __restrict__ Wout_lig, const float* __restrict__ Wv_pro,
    const float* __restrict__ Wout_pro, const float* __restrict__ Wv_lig,
    bf16_t* __restrict__ A1, bf16_t* __restrict__ B2,
    bf16_t* __restrict__ PtTL, bf16_t* __restrict__ PtTP){
  __shared__ float Sa[1088];
  __shared__ float Sb[1088];
  const int z = blockIdx.z;
  const float *A, *B; bf16_t* C;
  if      (z == 0){ A = Wq_lig;   B = Wk_pro; C = A1;   }
  else if (z == 1){ A = Wk_lig;   B = Wq_pro; C = B2;   }
  else if (z == 2){ A = Wout_lig; B = Wv_pro; C = PtTL; }
  else            { A = Wout_pro; B = Wv_lig; C = PtTP; }
  const int t  = threadIdx.x;
  const int tx = t & 15, ty = t >> 4;
  const int bm = blockIdx.x, bn = blockIdx.y;
  float acc[4][4] = {};
  if (z < 2){
    float (*As)[68] = (float(*)[68])Sa;
    float (*Bs)[68] = (float(*)[68])Sb;
    const int kk = t >> 4, c0 = (t & 15) << 2;
    for (int kt = 0; kt < DIM; kt += 16){
      float4 av = *reinterpret_cast<const float4*>(A + (size_t)(kt+kk)*DIM + bm*64 + c0);
      float4 bv = *reinterpret_cast<const float4*>(B + (size_t)(kt+kk)*DIM + bn*64 + c0);
      As[kk][c0+0]=av.x; As[kk][c0+1]=av.y; As[kk][c0+2]=av.z; As[kk][c0+3]=av.w;
      Bs[kk][c0+0]=bv.x; Bs[kk][c0+1]=bv.y; Bs[kk][c0+2]=bv.z; Bs[kk][c0+3]=bv.w;
      __syncthreads();
      #pragma unroll
      for (int k = 0; k < 16; k++){
        float a[4], b[4];
        #pragma unroll
        for (int i = 0; i < 4; i++) a[i] = As[k][ty*4+i];
        #pragma unroll
        for (int j = 0; j < 4; j++) b[j] = Bs[k][tx*4+j];
        #pragma unroll
        for (int i = 0; i < 4; i++)
          #pragma unroll
          for (int j = 0; j < 4; j++) acc[i][j] += a[i]*b[j];
      }
      __syncthreads();
    }
  } else {
    float (*As)[17] = (float(*)[17])Sa;
    float (*Bs)[68] = (float(*)[68])Sb;
    const int r  = t >> 2, k0 = (t & 3) << 2;
    const int kk = t >> 4, c0 = (t & 15) << 2;
    for (int kt = 0; kt < DIM; kt += 16){
      float4 av = *reinterpret_cast<const float4*>(A + (size_t)(bm*64+r)*DIM + kt + k0);
      float4 bv = *reinterpret_cast<const float4*>(B + (size_t)(kt+kk)*DIM + bn*64 + c0);
      As[r][k0+0]=av.x; As[r][k0+1]=av.y; As[r][k0+2]=av.z; As[r][k0+3]=av.w;
      Bs[kk][c0+0]=bv.x; Bs[kk][c0+1]=bv.y; Bs[kk][c0+2]=bv.z; Bs[kk][c0+3]=bv.w;
      __syncthreads();
      #pragma unroll
      for (int k = 0; k < 16; k++){
        float a[4], b[4];
        #pragma unroll
        for (int i = 0; i < 4; i++) a[i] = As[ty*4+i][k];
        #pragma unroll
        for (int j = 0; j < 4; j++) b[j] = Bs[k][tx*4+j];
        #pragma unroll
        for (int i = 0; i < 4; i++)
          #pragma unroll
          for (int j = 0; j < 4; j++) acc[i][j] += a[i]*b[j];
      }
      __syncthreads();
    }
  }
  #pragma unroll
  for (int i = 0; i < 4; i++){
    ushort4 o;
    o.x=f2bf(acc[i][0]); o.y=f2bf(acc[i][1]); o.z=f2bf(acc[i][2]); o.w=f2bf(acc[i][3]);
    *reinterpret_cast<ushort4*>(C + (size_t)(bm*64+ty*4+i)*DIM + bn*64 + tx*4) = o;
  }
}

// ---- two ligand projections in one launch ----
__global__ __launch_bounds__(256) void gemm2(
    const float* __restrict__ A, const bf16_t* __restrict__ Ba, const bf16_t* __restrict__ Bb,
    bf16_t* __restrict__ Ca, bf16_t* __restrict__ Cb){
  const bf16_t* B = blockIdx.z ? Bb : Ba;
  bf16_t*       C = blockIdx.z ? Cb : Ca;
  __shared__ float As[64][17];
  __shared__ float Bs[16][68];
  const int t  = threadIdx.x;
  const int r  = t >> 2, k0 = (t & 3) << 2;
  const int kk = t >> 4, c0 = (t & 15) << 2;
  const int tx = t & 15, ty = t >> 4;
  const int bm = blockIdx.x, bn = blockIdx.y;
  float acc[4][4] = {};
  for (int kt = 0; kt < DIM; kt += 16){
    float4 av = *reinterpret_cast<const float4*>(A + (size_t)(bm*64+r)*DIM + kt + k0);
    ushort4 bu = *reinterpret_cast<const ushort4*>(B + (size_t)(kt+kk)*DIM + bn*64 + c0);
    As[r][k0+0]=av.x; As[r][k0+1]=av.y; As[r][k0+2]=av.z; As[r][k0+3]=av.w;
    Bs[kk][c0+0]=bf2f(bu.x); Bs[kk][c0+1]=bf2f(bu.y);
    Bs[kk][c0+2]=bf2f(bu.z); Bs[kk][c0+3]=bf2f(bu.w);
    __syncthreads();
    #pragma unroll
    for (int k = 0; k < 16; k++){
      float a[4], b[4];
      #pragma unroll
      for (int i = 0; i < 4; i++) a[i] = As[ty*4+i][k];
      #pragma unroll
      for (int j = 0; j < 4; j++) b[j] = Bs[k][tx*4+j];
      #pragma unroll
      for (int i = 0; i < 4; i++)
        #pragma unroll
        for (int j = 0; j < 4; j++) acc[i][j] += a[i]*b[j];
    }
    __syncthreads();
  }
  #pragma unroll
  for (int i = 0; i < 4; i++){
    ushort4 o;
    o.x=f2bf(acc[i][0]); o.y=f2bf(acc[i][1]); o.z=f2bf(acc[i][2]); o.w=f2bf(acc[i][3]);
    *reinterpret_cast<ushort4*>(C + (size_t)(bm*64+ty*4+i)*DIM + bn*64 + tx*4) = o;
  }
}

// ==== ligand attention: 128 tiles x 8 key-splits = 1024 blocks ====
__global__ __launch_bounds__(128) void attn_lig(
    const bf16_t* __restrict__ Qb, const float* __restrict__ Kf,
    const float* __restrict__ posA, const float* __restrict__ posB,
    const int* __restrict__ batchA, const int* __restrict__ startB,
    float* __restrict__ dout, float* __restrict__ mlpart, int NK){
  __shared__ __align__(16) char raw[36864];   // Vlds [256][72] bf16; later Ob [2][16][256] f32
  __shared__ bf16_t Pbuf[2][16][40];
  __shared__ float  mlb[2][2][16];
  bf16_t* Vlds = (bf16_t*)raw;
  float*  Ob   = (float*)raw;
  float* Opart = dout + OPART_OFF;

  const int t = threadIdx.x, wl = t >> 6, lane = t & 63;
  const int qrow = lane & 15, q4 = lane >> 4;
  const int pidx = blockIdx.x, tile = pidx >> 3, split = pidx & 7;
  const int row0 = tile * 16;

  const int rb = batchA[row0 + qrow];
  const int j0 = startB[rb], j1 = startB[rb + 1];
  const float ax = posA[(size_t)(row0+qrow)*3+0];
  const float ay = posA[(size_t)(row0+qrow)*3+1];
  const float az = posA[(size_t)(row0+qrow)*3+2];
  const int kmin = startB[batchA[row0]];
  const int kmax = startB[batchA[row0 + 15] + 1];
  const int base = kmin & ~63;

  bf16x8 qf[8];
  #pragma unroll
  for (int s = 0; s < 8; s++)
    qf[s] = *reinterpret_cast<const bf16x8*>(Qb + (size_t)(row0+qrow)*DIM + s*32 + q4*8);

  f32x4 O[16];
  #pragma unroll
  for (int i = 0; i < 16; i++) O[i] = (f32x4){0.f,0.f,0.f,0.f};
  float m_ = -3.0e38f, l_ = 0.f;

  for (int c = base + split*64; c < kmax; c += 512){
    __syncthreads();
    {  // stage 64 keys x 256 dims fp32 -> bf16 transposed, batched loads
      const int key = t & 63, half = t >> 6;
      const float* src = Kf + (size_t)min(c + key, NK-1)*DIM + half*128;
      #pragma unroll
      for (int gch = 0; gch < 4; gch++){
        float4 tmp[8];
        #pragma unroll
        for (int u = 0; u < 8; u++)
          tmp[u] = *reinterpret_cast<const float4*>(src + gch*32 + u*4);
        #pragma unroll
        for (int u = 0; u < 8; u++){
          int d = half*128 + gch*32 + u*4;
          Vlds[(d+0)*72 + key] = f2bf(tmp[u].x);
          Vlds[(d+1)*72 + key] = f2bf(tmp[u].y);
          Vlds[(d+2)*72 + key] = f2bf(tmp[u].z);
          Vlds[(d+3)*72 + key] = f2bf(tmp[u].w);
        }
      }
    }
    __syncthreads();

    const int kc0 = c + wl*32, colbase = wl*32;
    f32x4 a0 = (f32x4){0.f,0.f,0.f,0.f}, a1 = a0;
    const float* kr0 = Kf + (size_t)min(kc0 + qrow,      NK-1)*DIM;
    const float* kr1 = Kf + (size_t)min(kc0 + 16 + qrow, NK-1)*DIM;
    #pragma unroll
    for (int s = 0; s < 8; s++){
      bf16x8 ka = ldfrag_f32(kr0 + s*32 + q4*8);
      bf16x8 kb = ldfrag_f32(kr1 + s*32 + q4*8);
      a0 = __builtin_amdgcn_mfma_f32_16x16x32_bf16(ka, qf[s], a0, 0, 0, 0);
      a1 = __builtin_amdgcn_mfma_f32_16x16x32_bf16(kb, qf[s], a1, 0, 0, 0);
    }
    float sc[2][4]; bool vm[2][4];
    float cm = -3.0e38f;
    #pragma unroll
    for (int h = 0; h < 2; h++)
      #pragma unroll
      for (int r = 0; r < 4; r++){
        int key = kc0 + h*16 + q4*4 + r;
        bool vld = (key >= j0) && (key < j1);
        int kc = min(key, NK-1);
        float bx = posB[(size_t)kc*3+0], by = posB[(size_t)kc*3+1], bz = posB[(size_t)kc*3+2];
        float dx = ax-bx, dy = ay-by, dz = az-bz;
        float dist = sqrtf(fmaxf(dx*dx + dy*dy + dz*dz, 1e-12f));
        float sv = (h ? a1[r] : a0[r]) * 0.0625f + __expf(-0.1f*dist);
        sc[h][r] = vld ? sv : -3.0e38f;
        vm[h][r] = vld;
        cm = fmaxf(cm, sc[h][r]);
      }
    cm = fmaxf(cm, __shfl_xor(cm, 16));
    cm = fmaxf(cm, __shfl_xor(cm, 32));
    float mn = fmaxf(m_, cm);
    float aa = __expf(m_ - mn);
    float p[2][4]; float ps = 0.f;
    #pragma unroll
    for (int h = 0; h < 2; h++)
      #pragma unroll
      for (int r = 0; r < 4; r++){
        p[h][r] = vm[h][r] ? __expf(sc[h][r] - mn) : 0.f;
        ps += p[h][r];
      }
    ps += __shfl_xor(ps, 16);
    ps += __shfl_xor(ps, 32);
    l_ = l_*aa + ps;
    m_ = mn;
    ushort4 w0, w1;
    w0.x=f2bf(p[0][0]); w0.y=f2bf(p[0][1]); w0.z=f2bf(p[0][2]); w0.w=f2bf(p[0][3]);
    w1.x=f2bf(p[1][0]); w1.y=f2bf(p[1][1]); w1.z=f2bf(p[1][2]); w1.w=f2bf(p[1][3]);
    *reinterpret_cast<ushort4*>(&Pbuf[wl][qrow][q4*4])      = w0;
    *reinterpret_cast<ushort4*>(&Pbuf[wl][qrow][16 + q4*4]) = w1;
    float af0 = __shfl(aa, q4*4+0), af1 = __shfl(aa, q4*4+1);
    float af2 = __shfl(aa, q4*4+2), af3 = __shfl(aa, q4*4+3);
    #pragma unroll
    for (int i = 0; i < 16; i++){
      O[i][0]*=af0; O[i][1]*=af1; O[i][2]*=af2; O[i][3]*=af3;
    }
    bf16x8 pa = *reinterpret_cast<const bf16x8*>(&Pbuf[wl][qrow][q4*8]);
    #pragma unroll
    for (int i = 0; i < 16; i++){
      const bf16_t* vp = Vlds + (size_t)(i*16 + qrow)*72 + colbase + q4*8;
      bf16x8 vb = *reinterpret_cast<const bf16x8*>(vp);
      O[i] = __builtin_amdgcn_mfma_f32_16x16x32_bf16(pa, vb, O[i], 0, 0, 0);
    }
  }

  // in-block 2-wave merge (un-normalized) -> write partial
  __syncthreads();
  if (lane < 16){ mlb[wl][0][lane] = m_; mlb[wl][1][lane] = l_; }
  #pragma unroll
  for (int i = 0; i < 16; i++)
    #pragma unroll
    for (int r = 0; r < 4; r++)
      Ob[wl*4096 + (q4*4+r)*256 + i*16 + qrow] = O[i][r];
  __syncthreads();
  for (int e = t; e < 4096; e += 128){
    int row = e >> 8, d = e & 255;
    float m0 = mlb[0][0][row], m1 = mlb[1][0][row];
    float mg = fmaxf(m0, m1);
    float f0 = __expf(m0 - mg), f1 = __expf(m1 - mg);
    Opart[(size_t)pidx*4096 + row*256 + d] = Ob[row*256 + d]*f0 + Ob[4096 + row*256 + d]*f1;
  }
  if (t < 16){
    float m0 = mlb[0][0][t], l0 = mlb[0][1][t];
    float m1 = mlb[1][0][t], l1 = mlb[1][1][t];
    float mg = fmaxf(m0, m1);
    mlpart[pidx*32 + t]      = mg;
    mlpart[pidx*32 + 16 + t] = l0*__expf(m0-mg) + l1*__expf(m1-mg);
  }
}

// ==== ligand merge (8 partials) + out-projection + residual + LN ====
__global__ __launch_bounds__(128) void merge_lig(
    const float* __restrict__ dpart, const float* __restrict__ mlpart,
    const bf16_t* __restrict__ PtT,
    const float* __restrict__ X, const float* __restrict__ bo,
    const float* __restrict__ g, const float* __restrict__ bb,
    float* __restrict__ out){
  __shared__ float ctxl[16*260];
  __shared__ float Yb[16*260];
  __shared__ float wgt[8][16];
  __shared__ float dens[16];
  const float* Opart = dpart + OPART_OFF;
  const int t = threadIdx.x, wl = t >> 6, lane = t & 63;
  const int qrow = lane & 15, q4 = lane >> 4;
  const int tile = blockIdx.x, row0 = tile*16;
  if (t < 16){
    float mm[8], ll[8], mg = -3.0e38f;
    #pragma unroll
    for (int s = 0; s < 8; s++){
      mm[s] = mlpart[(tile*8+s)*32 + t];
      ll[s] = mlpart[(tile*8+s)*32 + 16 + t];
      mg = fmaxf(mg, mm[s]);
    }
    float den = 0.f;
    #pragma unroll
    for (int s = 0; s < 8; s++){
      float w = __expf(mm[s] - mg);
      wgt[s][t] = w;
      den += ll[s]*w;
    }
    dens[t] = den;
  }
  __syncthreads();
  for (int e = t; e < 4096; e += 128){
    int row = e >> 8, d = e & 255;
    float acc = 0.f;
    #pragma unroll
    for (int s = 0; s < 8; s++)
      acc += Opart[((size_t)(tile*8+s))*4096 + row*256 + d] * wgt[s][row];
    float dd = dens[row];
    ctxl[row*260 + d] = (dd > 0.f) ? acc/dd : 0.f;
  }
  __syncthreads();
  f32x4 Y[8];
  #pragma unroll
  for (int i = 0; i < 8; i++) Y[i] = (f32x4){0.f,0.f,0.f,0.f};
  #pragma unroll
  for (int s = 0; s < 8; s++){
    bf16x8 ca, cl;
    hilo8(ctxl + qrow*260 + s*32 + q4*8, ca, cl);
    #pragma unroll
    for (int tt = 0; tt < 8; tt++){
      const bf16_t* pb = PtT + (size_t)((wl*8+tt)*16 + qrow)*DIM + s*32 + q4*8;
      bf16x8 mb = *reinterpret_cast<const bf16x8*>(pb);
      Y[tt] = __builtin_amdgcn_mfma_f32_16x16x32_bf16(ca, mb, Y[tt], 0, 0, 0);
      Y[tt] = __builtin_amdgcn_mfma_f32_16x16x32_bf16(cl, mb, Y[tt], 0, 0, 0);
    }
  }
  #pragma unroll
  for (int tt = 0; tt < 8; tt++)
    #pragma unroll
    for (int r = 0; r < 4; r++)
      Yb[(q4*4+r)*260 + (wl*8+tt)*16 + qrow] = Y[tt][r];
  __syncthreads();
  for (int i = 0; i < 8; i++){
    int r = wl*8 + i, grow = row0 + r;
    float4 yv = *reinterpret_cast<const float4*>(&Yb[r*260 + 4*lane]);
    float4 xv = *reinterpret_cast<const float4*>(X  + (size_t)grow*DIM + 4*lane);
    float4 bv = *reinterpret_cast<const float4*>(bo + 4*lane);
    float4 gv = *reinterpret_cast<const float4*>(g  + 4*lane);
    float4 b2 = *reinterpret_cast<const float4*>(bb + 4*lane);
    float v0 = xv.x + yv.x + bv.x, v1 = xv.y + yv.y + bv.y;
    float v2 = xv.z + yv.z + bv.z, v3 = xv.w + yv.w + bv.w;
    float sum = wave_sum(v0+v1+v2+v3);
    float ssq = wave_sum(v0*v0+v1*v1+v2*v2+v3*v3);
    float mu  = sum * (1.0f/DIM);
    float var = ssq * (1.0f/DIM) - mu*mu;
    float rr  = rsqrtf(fmaxf(var, 0.f) + 1e-5f);
    float4 o;
    o.x = (v0-mu)*rr*gv.x + b2.x;
    o.y = (v1-mu)*rr*gv.y + b2.y;
    o.z = (v2-mu)*rr*gv.z + b2.z;
    o.w = (v3-mu)*rr*gv.w + b2.w;
    *reinterpret_cast<float4*>(out + (size_t)grow*DIM + 4*lane) = o;
  }
}

// ==== protein attention: 1024 blocks x one 16-row tile, 2-wave key split ====
__global__ __launch_bounds__(128) void attn_pro(
    const float* __restrict__ Qf, const bf16_t* __restrict__ Kb,
    const float* __restrict__ Vf,
    const float* __restrict__ posA, const float* __restrict__ posB,
    const int* __restrict__ batchA, const int* __restrict__ startB,
    const bf16_t* __restrict__ PtT,
    const float* __restrict__ X, const float* __restrict__ bo,
    const float* __restrict__ g, const float* __restrict__ bb,
    float* __restrict__ out, int out_off, int NK){
  __shared__ __align__(16) char raw[36864];   // Vlds [256][72]; later Ob [2][16][256] f32
  __shared__ bf16_t Pbuf[2][16][40];
  __shared__ float  mlb[2][2][16];
  bf16_t* Vlds = (bf16_t*)raw;
  float*  Ob   = (float*)raw;

  const int t = threadIdx.x, wl = t >> 6, lane = t & 63;
  const int qrow = lane & 15, q4 = lane >> 4;
  const int row0 = blockIdx.x * 16;

  const int rb = batchA[row0 + qrow];
  const int j0 = startB[rb], j1 = startB[rb + 1];
  const float ax = posA[(size_t)(row0+qrow)*3+0];
  const float ay = posA[(size_t)(row0+qrow)*3+1];
  const float az = posA[(size_t)(row0+qrow)*3+2];
  const int kmin = startB[batchA[row0]];
  const int kmax = startB[batchA[row0 + 15] + 1];
  const int base = kmin & ~63;

  bf16x8 qf[8], ql[8];
  #pragma unroll
  for (int s = 0; s < 8; s++)
    hilo8(Qf + (size_t)(row0+qrow)*DIM + s*32 + q4*8, qf[s], ql[s]);

  f32x4 O[16];
  #pragma unroll
  for (int i = 0; i < 16; i++) O[i] = (f32x4){0.f,0.f,0.f,0.f};
  float m_ = -3.0e38f, l_ = 0.f;

  for (int c = base; c < kmax; c += 64){
    __syncthreads();
    {  // stage 64 keys x 256 dims fp32 -> bf16 transposed
      const int key = t & 63, half = t >> 6;
      const float* src = Vf + (size_t)min(c + key, NK-1)*DIM + half*128;
      #pragma unroll
      for (int gch = 0; gch < 4; gch++){
        float4 tmp[8];
        #pragma unroll
        for (int u = 0; u < 8; u++)
          tmp[u] = *reinterpret_cast<const float4*>(src + gch*32 + u*4);
        #pragma unroll
        for (int u = 0; u < 8; u++){
          int d = half*128 + gch*32 + u*4;
          Vlds[(d+0)*72 + key] = f2bf(tmp[u].x);
          Vlds[(d+1)*72 + key] = f2bf(tmp[u].y);
          Vlds[(d+2)*72 + key] = f2bf(tmp[u].z);
          Vlds[(d+3)*72 + key] = f2bf(tmp[u].w);
        }
      }
    }
    __syncthreads();

    const int kc0 = c + wl*32, colbase = wl*32;
    f32x4 a0 = (f32x4){0.f,0.f,0.f,0.f}, a1 = a0;
    const bf16_t* kr0 = Kb + (size_t)min(kc0 + qrow,      NK-1)*DIM;
    const bf16_t* kr1 = Kb + (size_t)min(kc0 + 16 + qrow, NK-1)*DIM;
    #pragma unroll
    for (int s = 0; s < 8; s++){
      bf16x8 ka = *reinterpret_cast<const bf16x8*>(kr0 + s*32 + q4*8);
      bf16x8 kb = *reinterpret_cast<const bf16x8*>(kr1 + s*32 + q4*8);
      a0 = __builtin_amdgcn_mfma_f32_16x16x32_bf16(ka, qf[s], a0, 0, 0, 0);
      a1 = __builtin_amdgcn_mfma_f32_16x16x32_bf16(kb, qf[s], a1, 0, 0, 0);
      a0 = __builtin_amdgcn_mfma_f32_16x16x32_bf16(ka, ql[s], a0, 0, 0, 0);
      a1 = __builtin_amdgcn_mfma_f32_16x16x32_bf16(kb, ql[s], a1, 0, 0, 0);
    }
    float sc[2][4]; bool vm[2][4];
    float cm = -3.0e38f;
    #pragma unroll
    for (int h = 0; h < 2; h++)
      #pragma unroll
      for (int r = 0; r < 4; r++){
        int key = kc0 + h*16 + q4*4 + r;
        bool vld = (key >= j0) && (key < j1);
        int kc = min(key, NK-1);
        float bx = posB[(size_t)kc*3+0], by = posB[(size_t)kc*3+1], bz = posB[(size_t)kc*3+2];
        float dx = ax-bx, dy = ay-by, dz = az-bz;
        float dist = sqrtf(fmaxf(dx*dx + dy*dy + dz*dz, 1e-12f));
        float sv = (h ? a1[r] : a0[r]) * 0.0625f + __expf(-0.1f*dist);
        sc[h][r] = vld ? sv : -3.0e38f;
        vm[h][r] = vld;
        cm = fmaxf(cm, sc[h][r]);
      }
    cm = fmaxf(cm, __shfl_xor(cm, 16));
    cm = fmaxf(cm, __shfl_xor(cm, 32));
    float mn = fmaxf(m_, cm);
    float aa = __expf(m_ - mn);
    float p[2][4]; float ps = 0.f;
    #pragma unroll
    for (int h = 0; h < 2; h++)
      #pragma unroll
      for (int r = 0; r < 4; r++){
        p[h][r] = vm[h][r] ? __expf(sc[h][r] - mn) : 0.f;
        ps += p[h][r];
      }
    ps += __shfl_xor(ps, 16);
    ps += __shfl_xor(ps, 32);
    l_ = l_*aa + ps;
    m_ = mn;
    ushort4 w0, w1;
    w0.x=f2bf(p[0][0]); w0.y=f2bf(p[0][1]); w0.z=f2bf(p[0][2]); w0.w=f2bf(p[0][3]);
    w1.x=f2bf(p[1][0]); w1.y=f2bf(p[1][1]); w1.z=f2bf(p[1][2]); w1.w=f2bf(p[1][3]);
    *reinterpret_cast<ushort4*>(&Pbuf[wl][qrow][q4*4])      = w0;
    *reinterpret_cast<ushort4*>(&Pbuf[wl][qrow][16 + q4*4]) = w1;
    float af0 = __shfl(aa, q4*4+0), af1 = __shfl(aa, q4*4+1);
    float af2 = __shfl(aa, q4*4+2), af3 = __shfl(aa, q4*4+3);
    #pragma unroll
    for (int i = 0; i < 16; i++){
      O[i][0]*=af0; O[i][1]*=af1; O[i][2]*=af2; O[i][3]*=af3;
    }
    bf16x8 pa = *reinterpret_cast<const bf16x8*>(&Pbuf[wl][qrow][q4*8]);
    #pragma unroll
    for (int i = 0; i < 16; i++){
      const bf16_t* vp = Vlds + (size_t)(i*16 + qrow)*72 + colbase + q4*8;
      bf16x8 vb = *reinterpret_cast<const bf16x8*>(vp);
      O[i] = __builtin_amdgcn_mfma_f32_16x16x32_bf16(pa, vb, O[i], 0, 0, 0);
    }
  }

  // in-block merge + normalize, in place (same-thread slots)
  __syncthreads();
  if (lane < 16){ mlb[wl][0][lane] = m_; mlb[wl][1][lane] = l_; }
  #pragma unroll
  for (int i = 0; i < 16; i++)
    #pragma unroll
    for (int r = 0; r < 4; r++)
      Ob[wl*4096 + (q4*4+r)*256 + i*16 + qrow] = O[i][r];
  __syncthreads();
  for (int e = t; e < 4096; e += 128){
    int row = e >> 8;
    float m0 = mlb[0][0][row], l0 = mlb[0][1][row];
    float m1 = mlb[1][0][row], l1 = mlb[1][1][row];
    float mg = fmaxf(m0, m1);
    float f0 = __expf(m0 - mg), f1 = __expf(m1 - mg);
    float den = l0*f0 + l1*f1;
    float v = Ob[e]*f0 + Ob[4096 + e]*f1;
    Ob[e] = (den > 0.f) ? v/den : 0.f;   // ctx, stride 256, same-thread slot
  }
  __syncthreads();

  // epilogue: Y = ctx_hi*M + ctx_lo*M ; ctx stride 256 (Ob[0]), Y into Ob[1] region
  const float* cw = Ob;                // [16][256]
  float* YB = Ob + 4096;               // [16][260]
  f32x4 Y[8];
  #pragma unroll
  for (int i = 0; i < 8; i++) Y[i] = (f32x4){0.f,0.f,0.f,0.f};
  #pragma unroll
  for (int s = 0; s < 8; s++){
    bf16x8 ca, cl;
    hilo8(cw + qrow*256 + s*32 + q4*8, ca, cl);
    #pragma unroll
    for (int tt = 0; tt < 8; tt++){
      const bf16_t* pb = PtT + (size_t)((wl*8+tt)*16 + qrow)*DIM + s*32 + q4*8;
      bf16x8 mb = *reinterpret_cast<const bf16x8*>(pb);
      Y[tt] = __builtin_amdgcn_mfma_f32_16x16x32_bf16(ca, mb, Y[tt], 0, 0, 0);
      Y[tt] = __builtin_amdgcn_mfma_f32_16x16x32_bf16(cl, mb, Y[tt], 0, 0, 0);
    }
  }
  __syncthreads();   // all ctx reads done before YB (disjoint region, but order waves)
  #pragma unroll
  for (int tt = 0; tt < 8; tt++)
    #pragma unroll
    for (int r = 0; r < 4; r++)
      YB[(q4*4+r)*260 + (wl*8+tt)*16 + qrow] = Y[tt][r];
  __syncthreads();

  for (int i = 0; i < 8; i++){
    int r = wl*8 + i, grow = row0 + r;
    float4 yv = *reinterpret_cast<const float4*>(&YB[r*260 + 4*lane]);
    float4 xv = *reinterpret_cast<const float4*>(X  + (size_t)grow*DIM + 4*lane);
    float4 bv = *reinterpret_cast<const float4*>(bo + 4*lane);
    float4 gv = *reinterpret_cast<const float4*>(g  + 4*lane);
    float4 b2 = *reinterpret_cast<const float4*>(bb + 4*lane);
    float v0 = xv.x + yv.x + bv.x, v1 = xv.y + yv.y + bv.y;
    float v2 = xv.z + yv.z + bv.z, v3 = xv.w + yv.w + bv.w;
    float sum = wave_sum(v0+v1+v2+v3);
    float ssq = wave_sum(v0*v0+v1*v1+v2*v2+v3*v3);
    float mu  = sum * (1.0f/DIM);
    float var = ssq * (1.0f/DIM) - mu*mu;
    float rr  = rsqrtf(fmaxf(var, 0.f) + 1e-5f);
    float4 o;
    o.x = (v0-mu)*rr*gv.x + b2.x;
    o.y = (v1-mu)*rr*gv.y + b2.y;
    o.z = (v2-mu)*rr*gv.z + b2.z;
    o.w = (v3-mu)*rr*gv.w + b2.w;
    *reinterpret_cast<float4*>(out + (size_t)out_off + (size_t)grow*DIM + 4*lane) = o;
  }
}

extern "C" void kernel_launch(void* const* d_in, const int* in_sizes, int n_in,
                              void* d_out, int out_size, void* d_ws, size_t ws_size,
                              hipStream_t stream){
  const float* lig      = (const float*)d_in[0];
  const float* pro      = (const float*)d_in[1];
  const float* lig_pos  = (const float*)d_in[2];
  const float* pro_pos  = (const float*)d_in[3];
  const int*   lig_batch= (const int*)d_in[4];
  const int*   pro_batch= (const int*)d_in[5];
  const float* Wq_lig   = (const float*)d_in[6];
  const float* Wk_pro   = (const float*)d_in[7];
  const float* Wv_pro   = (const float*)d_in[8];
  const float* Wq_pro   = (const float*)d_in[9];
  const float* Wk_lig   = (const float*)d_in[10];
  const float* Wv_lig   = (const float*)d_in[11];
  const float* Wout_lig = (const float*)d_in[12];
  const float* bout_lig = (const float*)d_in[13];
  const float* Wout_pro = (const float*)d_in[14];
  const float* bout_pro = (const float*)d_in[15];
  const float* g_lig    = (const float*)d_in[16];
  const float* b_lig    = (const float*)d_in[17];
  const float* g_pro    = (const float*)d_in[18];
  const float* b_pro    = (const float*)d_in[19];

  // ws (~2.75 MB; proven safe ≤3.6 MB): ints, 4 weight products, G, T_lig, mlpart
  int* ib        = (int*)d_ws;
  int* lig_start = ib + 16;
  int* pro_start = ib + 56;
  bf16_t* wsb  = ((bf16_t*)d_ws) + 256;
  bf16_t* A1   = wsb;                         // Wq_lig^T Wk_pro
  bf16_t* B2   = A1   + DIM*DIM;              // Wk_lig^T Wq_pro
  bf16_t* PtTL = B2   + DIM*DIM;              // Wout_lig @ Wv_pro  (= M_lig^T)
  bf16_t* PtTP = PtTL + DIM*DIM;              // Wout_pro @ Wv_lig  (= M_pro^T)
  bf16_t* G    = PtTP + DIM*DIM;              // lig @ B2   [2048][256]  (pro-side K)
  bf16_t* T_lig= G    + (size_t)NLr*DIM;      // lig @ A1   [2048][256]  (lig-side Q)
  float* mlpart= (float*)(T_lig + (size_t)NLr*DIM);   // 1024*32 floats

  float* outp = (float*)d_out;

  hipLaunchKernelGGL(bounds_kernel, dim3(1), dim3(64), 0, stream,
                     lig_batch, pro_batch, lig_start, pro_start);
  hipLaunchKernelGGL(wprod4, dim3(4,4,4), dim3(256), 0, stream,
                     Wq_lig, Wk_pro, Wk_lig, Wq_pro, Wout_lig, Wv_pro, Wout_pro, Wv_lig,
                     A1, B2, PtTL, PtTP);
  hipLaunchKernelGGL(gemm2, dim3(NLr/64, 4, 2), dim3(256), 0, stream,
                     lig, A1, B2, T_lig, G);

  // ligand <- protein: 128 tiles x 8 splits, partials, then merge
  hipLaunchKernelGGL(attn_lig, dim3(NLr/16*8), dim3(128), 0, stream,
                     T_lig, pro, lig_pos, pro_pos, lig_batch, pro_start, outp, mlpart, NPr);
  hipLaunchKernelGGL(merge_lig, dim3(NLr/16), dim3(128), 0, stream,
                     outp, mlpart, PtTL, lig, bout_lig, g_lig, b_lig, outp);

  // protein <- ligand (overwrites partial region only after merge consumed it)
  hipLaunchKernelGGL(attn_pro, dim3(NPr/16), dim3(128), 0, stream,
                     pro, G, lig, pro_pos, lig_pos, pro_batch, lig_start, PtTP,
                     pro, bout_pro, g_pro, b_pro, outp, NLr*DIM, NLr);
}

// Round 13
// 263.016 us; speedup vs baseline: 1.0986x; 1.0986x over previous
//
#include <hip/hip_runtime.h>

static constexpr int NLr = 2048;    // ligand rows
static constexpr int NPr = 16384;   // protein rows
static constexpr int DIM = 256;     // feature dim
static constexpr int NB  = 32;      // batch count

typedef unsigned short bf16_t;
using bf16x8 = __attribute__((ext_vector_type(8))) short;
using f32x4  = __attribute__((ext_vector_type(4))) float;

__device__ inline float bf2f(bf16_t u){
  union { unsigned int i; float f; } c; c.i = ((unsigned int)u) << 16; return c.f;
}
__device__ inline bf16_t f2bf(float f){
  union { float f; unsigned int i; } c; c.f = f;
  unsigned int x = c.i;
  return (bf16_t)((x + 0x7fffu + ((x >> 16) & 1u)) >> 16);  // RNE
}
__device__ inline float wave_sum(float x){
  #pragma unroll
  for (int off = 32; off; off >>= 1) x += __shfl_xor(x, off, 64);
  return x;
}
__device__ inline bf16x8 ldfrag_f32(const float* p){
  float4 a = *reinterpret_cast<const float4*>(p);
  float4 b = *reinterpret_cast<const float4*>(p + 4);
  bf16x8 r;
  r[0]=(short)f2bf(a.x); r[1]=(short)f2bf(a.y); r[2]=(short)f2bf(a.z); r[3]=(short)f2bf(a.w);
  r[4]=(short)f2bf(b.x); r[5]=(short)f2bf(b.y); r[6]=(short)f2bf(b.z); r[7]=(short)f2bf(b.w);
  return r;
}
// fp32 -> (hi, lo) bf16 pair
__device__ inline void hilo8(const float* p, bf16x8& hi, bf16x8& lo){
  #pragma unroll
  for (int i = 0; i < 8; i++){
    float v = p[i];
    bf16_t h = f2bf(v);
    hi[i] = (short)h;
    lo[i] = (short)f2bf(v - bf2f(h));
  }
}

// lig partials: O-partials in d_out tail (pro-out region, consumed before attn_pro)
static constexpr int OPART_OFF = 524288;   // floats; 1024 * 4096 ends at d_out end

// ---- batch block boundaries ----
__global__ void bounds_kernel(const int* __restrict__ lb, const int* __restrict__ pb,
                              int* __restrict__ ls, int* __restrict__ ps){
  int t = threadIdx.x;
  if (t <= NB){
    int lo = 0, hi = NLr;
    while (lo < hi){ int mid = (lo + hi) >> 1; if (lb[mid] < t) lo = mid + 1; else hi = mid; }
    ls[t] = lo;
    lo = 0; hi = NPr;
    while (lo < hi){ int mid = (lo + hi) >> 1; if (pb[mid] < t) lo = mid + 1; else hi = mid; }
    ps[t] = lo;
  }
}

// ---- 4 weight products in one launch: z<2 -> A^T B ; z>=2 -> A B ----
__global__ __launch_bounds__(256) void wprod4(
    const float* __restrict__ Wq_lig, const float* __restrict__ Wk_pro,
    const float* __restrict__ Wk_lig, const float* __restrict__ Wq_pro,
    const float* __restrict__ Wout_lig, const float* __restrict__ Wv_pro,
    const float* __restrict__ Wout_pro, const float* __restrict__ Wv_lig,
    bf16_t* __restrict__ A1, bf16_t* __restrict__ B2,
    bf16_t* __restrict__ PtTL, bf16_t* __restrict__ PtTP){
  __shared__ float Sa[1088];
  __shared__ float Sb[1088];
  const int z = blockIdx.z;
  const float *A, *B; bf16_t* C;
  if      (z == 0){ A = Wq_lig;   B = Wk_pro; C = A1;   }
  else if (z == 1){ A = Wk_lig;   B = Wq_pro; C = B2;   }
  else if (z == 2){ A = Wout_lig; B = Wv_pro; C = PtTL; }
  else            { A = Wout_pro; B = Wv_lig; C = PtTP; }
  const int t  = threadIdx.x;
  const int tx = t & 15, ty = t >> 4;
  const int bm = blockIdx.x, bn = blockIdx.y;
  float acc[4][4] = {};
  if (z < 2){
    float (*As)[68] = (float(*)[68])Sa;
    float (*Bs)[68] = (float(*)[68])Sb;
    const int kk = t >> 4, c0 = (t & 15) << 2;
    for (int kt = 0; kt < DIM; kt += 16){
      float4 av = *reinterpret_cast<const float4*>(A + (size_t)(kt+kk)*DIM + bm*64 + c0);
      float4 bv = *reinterpret_cast<const float4*>(B + (size_t)(kt+kk)*DIM + bn*64 + c0);
      As[kk][c0+0]=av.x; As[kk][c0+1]=av.y; As[kk][c0+2]=av.z; As[kk][c0+3]=av.w;
      Bs[kk][c0+0]=bv.x; Bs[kk][c0+1]=bv.y; Bs[kk][c0+2]=bv.z; Bs[kk][c0+3]=bv.w;
      __syncthreads();
      #pragma unroll
      for (int k = 0; k < 16; k++){
        float a[4], b[4];
        #pragma unroll
        for (int i = 0; i < 4; i++) a[i] = As[k][ty*4+i];
        #pragma unroll
        for (int j = 0; j < 4; j++) b[j] = Bs[k][tx*4+j];
        #pragma unroll
        for (int i = 0; i < 4; i++)
          #pragma unroll
          for (int j = 0; j < 4; j++) acc[i][j] += a[i]*b[j];
      }
      __syncthreads();
    }
  } else {
    float (*As)[17] = (float(*)[17])Sa;
    float (*Bs)[68] = (float(*)[68])Sb;
    const int r  = t >> 2, k0 = (t & 3) << 2;
    const int kk = t >> 4, c0 = (t & 15) << 2;
    for (int kt = 0; kt < DIM; kt += 16){
      float4 av = *reinterpret_cast<const float4*>(A + (size_t)(bm*64+r)*DIM + kt + k0);
      float4 bv = *reinterpret_cast<const float4*>(B + (size_t)(kt+kk)*DIM + bn*64 + c0);
      As[r][k0+0]=av.x; As[r][k0+1]=av.y; As[r][k0+2]=av.z; As[r][k0+3]=av.w;
      Bs[kk][c0+0]=bv.x; Bs[kk][c0+1]=bv.y; Bs[kk][c0+2]=bv.z; Bs[kk][c0+3]=bv.w;
      __syncthreads();
      #pragma unroll
      for (int k = 0; k < 16; k++){
        float a[4], b[4];
        #pragma unroll
        for (int i = 0; i < 4; i++) a[i] = As[ty*4+i][k];
        #pragma unroll
        for (int j = 0; j < 4; j++) b[j] = Bs[k][tx*4+j];
        #pragma unroll
        for (int i = 0; i < 4; i++)
          #pragma unroll
          for (int j = 0; j < 4; j++) acc[i][j] += a[i]*b[j];
      }
      __syncthreads();
    }
  }
  #pragma unroll
  for (int i = 0; i < 4; i++){
    ushort4 o;
    o.x=f2bf(acc[i][0]); o.y=f2bf(acc[i][1]); o.z=f2bf(acc[i][2]); o.w=f2bf(acc[i][3]);
    *reinterpret_cast<ushort4*>(C + (size_t)(bm*64+ty*4+i)*DIM + bn*64 + tx*4) = o;
  }
}

// ---- two ligand projections in one launch ----
__global__ __launch_bounds__(256) void gemm2(
    const float* __restrict__ A, const bf16_t* __restrict__ Ba, const bf16_t* __restrict__ Bb,
    bf16_t* __restrict__ Ca, bf16_t* __restrict__ Cb){
  const bf16_t* B = blockIdx.z ? Bb : Ba;
  bf16_t*       C = blockIdx.z ? Cb : Ca;
  __shared__ float As[64][17];
  __shared__ float Bs[16][68];
  const int t  = threadIdx.x;
  const int r  = t >> 2, k0 = (t & 3) << 2;
  const int kk = t >> 4, c0 = (t & 15) << 2;
  const int tx = t & 15, ty = t >> 4;
  const int bm = blockIdx.x, bn = blockIdx.y;
  float acc[4][4] = {};
  for (int kt = 0; kt < DIM; kt += 16){
    float4 av = *reinterpret_cast<const float4*>(A + (size_t)(bm*64+r)*DIM + kt + k0);
    ushort4 bu = *reinterpret_cast<const ushort4*>(B + (size_t)(kt+kk)*DIM + bn*64 + c0);
    As[r][k0+0]=av.x; As[r][k0+1]=av.y; As[r][k0+2]=av.z; As[r][k0+3]=av.w;
    Bs[kk][c0+0]=bf2f(bu.x); Bs[kk][c0+1]=bf2f(bu.y);
    Bs[kk][c0+2]=bf2f(bu.z); Bs[kk][c0+3]=bf2f(bu.w);
    __syncthreads();
    #pragma unroll
    for (int k = 0; k < 16; k++){
      float a[4], b[4];
      #pragma unroll
      for (int i = 0; i < 4; i++) a[i] = As[ty*4+i][k];
      #pragma unroll
      for (int j = 0; j < 4; j++) b[j] = Bs[k][tx*4+j];
      #pragma unroll
      for (int i = 0; i < 4; i++)
        #pragma unroll
        for (int j = 0; j < 4; j++) acc[i][j] += a[i]*b[j];
    }
    __syncthreads();
  }
  #pragma unroll
  for (int i = 0; i < 4; i++){
    ushort4 o;
    o.x=f2bf(acc[i][0]); o.y=f2bf(acc[i][1]); o.z=f2bf(acc[i][2]); o.w=f2bf(acc[i][3]);
    *reinterpret_cast<ushort4*>(C + (size_t)(bm*64+ty*4+i)*DIM + bn*64 + tx*4) = o;
  }
}

// ==== ligand attention: 128 tiles x 8 key-splits = 1024 blocks ====
__global__ __launch_bounds__(128) void attn_lig(
    const bf16_t* __restrict__ Qb, const float* __restrict__ Kf,
    const float* __restrict__ posA, const float* __restrict__ posB,
    const int* __restrict__ batchA, const int* __restrict__ startB,
    float* __restrict__ dout, float* __restrict__ mlpart, int NK){
  __shared__ __align__(16) char raw[36864];   // Vlds [256][72] bf16; later Ob [2][16][256] f32
  __shared__ bf16_t Pbuf[2][16][40];
  __shared__ float  mlb[2][2][16];
  bf16_t* Vlds = (bf16_t*)raw;
  float*  Ob   = (float*)raw;
  float* Opart = dout + OPART_OFF;

  const int t = threadIdx.x, wl = t >> 6, lane = t & 63;
  const int qrow = lane & 15, q4 = lane >> 4;
  const int pidx = blockIdx.x, tile = pidx >> 3, split = pidx & 7;
  const int row0 = tile * 16;

  const int rb = batchA[row0 + qrow];
  const int j0 = startB[rb], j1 = startB[rb + 1];
  const float ax = posA[(size_t)(row0+qrow)*3+0];
  const float ay = posA[(size_t)(row0+qrow)*3+1];
  const float az = posA[(size_t)(row0+qrow)*3+2];
  const int kmin = startB[batchA[row0]];
  const int kmax = startB[batchA[row0 + 15] + 1];
  const int base = kmin & ~63;

  bf16x8 qf[8];
  #pragma unroll
  for (int s = 0; s < 8; s++)
    qf[s] = *reinterpret_cast<const bf16x8*>(Qb + (size_t)(row0+qrow)*DIM + s*32 + q4*8);

  f32x4 O[16];
  #pragma unroll
  for (int i = 0; i < 16; i++) O[i] = (f32x4){0.f,0.f,0.f,0.f};
  float m_ = -3.0e38f, l_ = 0.f;

  for (int c = base + split*64; c < kmax; c += 512){
    __syncthreads();
    {  // stage 64 keys x 256 dims fp32 -> bf16 transposed, batched loads
      const int key = t & 63, half = t >> 6;
      const float* src = Kf + (size_t)min(c + key, NK-1)*DIM + half*128;
      #pragma unroll
      for (int gch = 0; gch < 4; gch++){
        float4 tmp[8];
        #pragma unroll
        for (int u = 0; u < 8; u++)
          tmp[u] = *reinterpret_cast<const float4*>(src + gch*32 + u*4);
        #pragma unroll
        for (int u = 0; u < 8; u++){
          int d = half*128 + gch*32 + u*4;
          Vlds[(d+0)*72 + key] = f2bf(tmp[u].x);
          Vlds[(d+1)*72 + key] = f2bf(tmp[u].y);
          Vlds[(d+2)*72 + key] = f2bf(tmp[u].z);
          Vlds[(d+3)*72 + key] = f2bf(tmp[u].w);
        }
      }
    }
    __syncthreads();

    const int kc0 = c + wl*32, colbase = wl*32;
    f32x4 a0 = (f32x4){0.f,0.f,0.f,0.f}, a1 = a0;
    const float* kr0 = Kf + (size_t)min(kc0 + qrow,      NK-1)*DIM;
    const float* kr1 = Kf + (size_t)min(kc0 + 16 + qrow, NK-1)*DIM;
    #pragma unroll
    for (int s = 0; s < 8; s++){
      bf16x8 ka = ldfrag_f32(kr0 + s*32 + q4*8);
      bf16x8 kb = ldfrag_f32(kr1 + s*32 + q4*8);
      a0 = __builtin_amdgcn_mfma_f32_16x16x32_bf16(ka, qf[s], a0, 0, 0, 0);
      a1 = __builtin_amdgcn_mfma_f32_16x16x32_bf16(kb, qf[s], a1, 0, 0, 0);
    }
    float sc[2][4]; bool vm[2][4];
    float cm = -3.0e38f;
    #pragma unroll
    for (int h = 0; h < 2; h++)
      #pragma unroll
      for (int r = 0; r < 4; r++){
        int key = kc0 + h*16 + q4*4 + r;
        bool vld = (key >= j0) && (key < j1);
        int kc = min(key, NK-1);
        float bx = posB[(size_t)kc*3+0], by = posB[(size_t)kc*3+1], bz = posB[(size_t)kc*3+2];
        float dx = ax-bx, dy = ay-by, dz = az-bz;
        float dist = sqrtf(fmaxf(dx*dx + dy*dy + dz*dz, 1e-12f));
        float sv = (h ? a1[r] : a0[r]) * 0.0625f + __expf(-0.1f*dist);
        sc[h][r] = vld ? sv : -3.0e38f;
        vm[h][r] = vld;
        cm = fmaxf(cm, sc[h][r]);
      }
    cm = fmaxf(cm, __shfl_xor(cm, 16));
    cm = fmaxf(cm, __shfl_xor(cm, 32));
    float mn = fmaxf(m_, cm);
    float aa = __expf(m_ - mn);
    float p[2][4]; float ps = 0.f;
    #pragma unroll
    for (int h = 0; h < 2; h++)
      #pragma unroll
      for (int r = 0; r < 4; r++){
        p[h][r] = vm[h][r] ? __expf(sc[h][r] - mn) : 0.f;
        ps += p[h][r];
      }
    ps += __shfl_xor(ps, 16);
    ps += __shfl_xor(ps, 32);
    l_ = l_*aa + ps;
    m_ = mn;
    ushort4 w0, w1;
    w0.x=f2bf(p[0][0]); w0.y=f2bf(p[0][1]); w0.z=f2bf(p[0][2]); w0.w=f2bf(p[0][3]);
    w1.x=f2bf(p[1][0]); w1.y=f2bf(p[1][1]); w1.z=f2bf(p[1][2]); w1.w=f2bf(p[1][3]);
    *reinterpret_cast<ushort4*>(&Pbuf[wl][qrow][q4*4])      = w0;
    *reinterpret_cast<ushort4*>(&Pbuf[wl][qrow][16 + q4*4]) = w1;
    float af0 = __shfl(aa, q4*4+0), af1 = __shfl(aa, q4*4+1);
    float af2 = __shfl(aa, q4*4+2), af3 = __shfl(aa, q4*4+3);
    #pragma unroll
    for (int i = 0; i < 16; i++){
      O[i][0]*=af0; O[i][1]*=af1; O[i][2]*=af2; O[i][3]*=af3;
    }
    bf16x8 pa = *reinterpret_cast<const bf16x8*>(&Pbuf[wl][qrow][q4*8]);
    #pragma unroll
    for (int i = 0; i < 16; i++){
      const bf16_t* vp = Vlds + (size_t)(i*16 + qrow)*72 + colbase + q4*8;
      bf16x8 vb = *reinterpret_cast<const bf16x8*>(vp);
      O[i] = __builtin_amdgcn_mfma_f32_16x16x32_bf16(pa, vb, O[i], 0, 0, 0);
    }
  }

  // in-block 2-wave merge (un-normalized) -> write partial
  __syncthreads();
  if (lane < 16){ mlb[wl][0][lane] = m_; mlb[wl][1][lane] = l_; }
  #pragma unroll
  for (int i = 0; i < 16; i++)
    #pragma unroll
    for (int r = 0; r < 4; r++)
      Ob[wl*4096 + (q4*4+r)*256 + i*16 + qrow] = O[i][r];
  __syncthreads();
  for (int e = t; e < 4096; e += 128){
    int row = e >> 8, d = e & 255;
    float m0 = mlb[0][0][row], m1 = mlb[1][0][row];
    float mg = fmaxf(m0, m1);
    float f0 = __expf(m0 - mg), f1 = __expf(m1 - mg);
    Opart[(size_t)pidx*4096 + row*256 + d] = Ob[row*256 + d]*f0 + Ob[4096 + row*256 + d]*f1;
  }
  if (t < 16){
    float m0 = mlb[0][0][t], l0 = mlb[0][1][t];
    float m1 = mlb[1][0][t], l1 = mlb[1][1][t];
    float mg = fmaxf(m0, m1);
    mlpart[pidx*32 + t]      = mg;
    mlpart[pidx*32 + 16 + t] = l0*__expf(m0-mg) + l1*__expf(m1-mg);
  }
}

// ==== ligand merge (8 partials) + out-projection + residual + LN ====
__global__ __launch_bounds__(128) void merge_lig(
    const float* __restrict__ dpart, const float* __restrict__ mlpart,
    const bf16_t* __restrict__ PtT,
    const float* __restrict__ X, const float* __restrict__ bo,
    const float* __restrict__ g, const float* __restrict__ bb,
    float* __restrict__ out){
  __shared__ float ctxl[16*260];
  __shared__ float Yb[16*260];
  __shared__ float wgt[8][16];
  __shared__ float dens[16];
  const float* Opart = dpart + OPART_OFF;
  const int t = threadIdx.x, wl = t >> 6, lane = t & 63;
  const int qrow = lane & 15, q4 = lane >> 4;
  const int tile = blockIdx.x, row0 = tile*16;
  if (t < 16){
    float mm[8], ll[8], mg = -3.0e38f;
    #pragma unroll
    for (int s = 0; s < 8; s++){
      mm[s] = mlpart[(tile*8+s)*32 + t];
      ll[s] = mlpart[(tile*8+s)*32 + 16 + t];
      mg = fmaxf(mg, mm[s]);
    }
    float den = 0.f;
    #pragma unroll
    for (int s = 0; s < 8; s++){
      float w = __expf(mm[s] - mg);
      wgt[s][t] = w;
      den += ll[s]*w;
    }
    dens[t] = den;
  }
  __syncthreads();
  for (int e = t; e < 4096; e += 128){
    int row = e >> 8, d = e & 255;
    float acc = 0.f;
    #pragma unroll
    for (int s = 0; s < 8; s++)
      acc += Opart[((size_t)(tile*8+s))*4096 + row*256 + d] * wgt[s][row];
    float dd = dens[row];
    ctxl[row*260 + d] = (dd > 0.f) ? acc/dd : 0.f;
  }
  __syncthreads();
  f32x4 Y[8];
  #pragma unroll
  for (int i = 0; i < 8; i++) Y[i] = (f32x4){0.f,0.f,0.f,0.f};
  #pragma unroll
  for (int s = 0; s < 8; s++){
    bf16x8 ca, cl;
    hilo8(ctxl + qrow*260 + s*32 + q4*8, ca, cl);
    #pragma unroll
    for (int tt = 0; tt < 8; tt++){
      const bf16_t* pb = PtT + (size_t)((wl*8+tt)*16 + qrow)*DIM + s*32 + q4*8;
      bf16x8 mb = *reinterpret_cast<const bf16x8*>(pb);
      Y[tt] = __builtin_amdgcn_mfma_f32_16x16x32_bf16(ca, mb, Y[tt], 0, 0, 0);
      Y[tt] = __builtin_amdgcn_mfma_f32_16x16x32_bf16(cl, mb, Y[tt], 0, 0, 0);
    }
  }
  #pragma unroll
  for (int tt = 0; tt < 8; tt++)
    #pragma unroll
    for (int r = 0; r < 4; r++)
      Yb[(q4*4+r)*260 + (wl*8+tt)*16 + qrow] = Y[tt][r];
  __syncthreads();
  for (int i = 0; i < 8; i++){
    int r = wl*8 + i, grow = row0 + r;
    float4 yv = *reinterpret_cast<const float4*>(&Yb[r*260 + 4*lane]);
    float4 xv = *reinterpret_cast<const float4*>(X  + (size_t)grow*DIM + 4*lane);
    float4 bv = *reinterpret_cast<const float4*>(bo + 4*lane);
    float4 gv = *reinterpret_cast<const float4*>(g  + 4*lane);
    float4 b2 = *reinterpret_cast<const float4*>(bb + 4*lane);
    float v0 = xv.x + yv.x + bv.x, v1 = xv.y + yv.y + bv.y;
    float v2 = xv.z + yv.z + bv.z, v3 = xv.w + yv.w + bv.w;
    float sum = wave_sum(v0+v1+v2+v3);
    float ssq = wave_sum(v0*v0+v1*v1+v2*v2+v3*v3);
    float mu  = sum * (1.0f/DIM);
    float var = ssq * (1.0f/DIM) - mu*mu;
    float rr  = rsqrtf(fmaxf(var, 0.f) + 1e-5f);
    float4 o;
    o.x = (v0-mu)*rr*gv.x + b2.x;
    o.y = (v1-mu)*rr*gv.y + b2.y;
    o.z = (v2-mu)*rr*gv.z + b2.z;
    o.w = (v3-mu)*rr*gv.w + b2.w;
    *reinterpret_cast<float4*>(out + (size_t)grow*DIM + 4*lane) = o;
  }
}

// ==== protein attention (round-11 proven version): 512 blocks, 2 independent
// per-wave 16-row tiles, shared 32-key staging ====
__global__ __launch_bounds__(128) void attn_pro(
    const float* __restrict__ Qf, const bf16_t* __restrict__ Kb,
    const float* __restrict__ Vf,
    const float* __restrict__ posA, const float* __restrict__ posB,
    const int* __restrict__ batchA, const int* __restrict__ startB,
    const bf16_t* __restrict__ PtT,
    const float* __restrict__ X, const float* __restrict__ bo,
    const float* __restrict__ g, const float* __restrict__ bb,
    float* __restrict__ out, int out_off, int NK){
  __shared__ __align__(16) char raw[33280];  // Vlds [256][40] bf16; later ctxl [2][16][260] f32
  __shared__ bf16_t Pbuf[2][16][40];
  bf16_t* Vlds = (bf16_t*)raw;
  float*  ctxl = (float*)raw;

  const int t = threadIdx.x, wl = t >> 6, lane = t & 63;
  const int qrow = lane & 15, q4 = lane >> 4;
  const int row0b = blockIdx.x * 32, row0 = row0b + wl*16;

  const int rb = batchA[row0 + qrow];
  const int j0 = startB[rb], j1 = startB[rb + 1];
  const float ax = posA[(size_t)(row0+qrow)*3+0];
  const float ay = posA[(size_t)(row0+qrow)*3+1];
  const float az = posA[(size_t)(row0+qrow)*3+2];
  const int kmin = startB[batchA[row0b]];
  const int kmax = startB[batchA[row0b + 31] + 1];
  const int base = kmin & ~31;

  bf16x8 qf[8], ql[8];
  #pragma unroll
  for (int s = 0; s < 8; s++)
    hilo8(Qf + (size_t)(row0+qrow)*DIM + s*32 + q4*8, qf[s], ql[s]);

  f32x4 O[16];
  #pragma unroll
  for (int i = 0; i < 16; i++) O[i] = (f32x4){0.f,0.f,0.f,0.f};
  float m_ = -3.0e38f, l_ = 0.f;

  for (int c = base; c < kmax; c += 32){
    __syncthreads();
    {  // stage 32 keys x 256 dims from fp32, batched
      const int key = t & 31, qtr = t >> 5;
      const float* src = Vf + (size_t)min(c + key, NK-1)*DIM + qtr*64;
      #pragma unroll
      for (int gch = 0; gch < 2; gch++){
        float4 tmp[8];
        #pragma unroll
        for (int u = 0; u < 8; u++)
          tmp[u] = *reinterpret_cast<const float4*>(src + gch*32 + u*4);
        #pragma unroll
        for (int u = 0; u < 8; u++){
          int d = qtr*64 + gch*32 + u*4;
          Vlds[(d+0)*40 + key] = f2bf(tmp[u].x);
          Vlds[(d+1)*40 + key] = f2bf(tmp[u].y);
          Vlds[(d+2)*40 + key] = f2bf(tmp[u].z);
          Vlds[(d+3)*40 + key] = f2bf(tmp[u].w);
        }
      }
    }
    __syncthreads();

    f32x4 a0 = (f32x4){0.f,0.f,0.f,0.f}, a1 = a0;
    const bf16_t* kr0 = Kb + (size_t)min(c + qrow,      NK-1)*DIM;
    const bf16_t* kr1 = Kb + (size_t)min(c + 16 + qrow, NK-1)*DIM;
    #pragma unroll
    for (int s = 0; s < 8; s++){
      bf16x8 ka = *reinterpret_cast<const bf16x8*>(kr0 + s*32 + q4*8);
      bf16x8 kb = *reinterpret_cast<const bf16x8*>(kr1 + s*32 + q4*8);
      a0 = __builtin_amdgcn_mfma_f32_16x16x32_bf16(ka, qf[s], a0, 0, 0, 0);
      a1 = __builtin_amdgcn_mfma_f32_16x16x32_bf16(kb, qf[s], a1, 0, 0, 0);
      a0 = __builtin_amdgcn_mfma_f32_16x16x32_bf16(ka, ql[s], a0, 0, 0, 0);
      a1 = __builtin_amdgcn_mfma_f32_16x16x32_bf16(kb, ql[s], a1, 0, 0, 0);
    }
    float sc[2][4]; bool vm[2][4];
    float cm = -3.0e38f;
    #pragma unroll
    for (int h = 0; h < 2; h++)
      #pragma unroll
      for (int r = 0; r < 4; r++){
        int key = c + h*16 + q4*4 + r;
        bool vld = (key >= j0) && (key < j1);
        int kc = min(key, NK-1);
        float bx = posB[(size_t)kc*3+0], by = posB[(size_t)kc*3+1], bz = posB[(size_t)kc*3+2];
        float dx = ax-bx, dy = ay-by, dz = az-bz;
        float dist = sqrtf(fmaxf(dx*dx + dy*dy + dz*dz, 1e-12f));
        float sv = (h ? a1[r] : a0[r]) * 0.0625f + __expf(-0.1f*dist);
        sc[h][r] = vld ? sv : -3.0e38f;
        vm[h][r] = vld;
        cm = fmaxf(cm, sc[h][r]);
      }
    cm = fmaxf(cm, __shfl_xor(cm, 16));
    cm = fmaxf(cm, __shfl_xor(cm, 32));
    float mn = fmaxf(m_, cm);
    float aa = __expf(m_ - mn);
    float p[2][4]; float ps = 0.f;
    #pragma unroll
    for (int h = 0; h < 2; h++)
      #pragma unroll
      for (int r = 0; r < 4; r++){
        p[h][r] = vm[h][r] ? __expf(sc[h][r] - mn) : 0.f;
        ps += p[h][r];
      }
    ps += __shfl_xor(ps, 16);
    ps += __shfl_xor(ps, 32);
    l_ = l_*aa + ps;
    m_ = mn;
    ushort4 w0, w1;
    w0.x=f2bf(p[0][0]); w0.y=f2bf(p[0][1]); w0.z=f2bf(p[0][2]); w0.w=f2bf(p[0][3]);
    w1.x=f2bf(p[1][0]); w1.y=f2bf(p[1][1]); w1.z=f2bf(p[1][2]); w1.w=f2bf(p[1][3]);
    *reinterpret_cast<ushort4*>(&Pbuf[wl][qrow][q4*4])      = w0;
    *reinterpret_cast<ushort4*>(&Pbuf[wl][qrow][16 + q4*4]) = w1;
    float af0 = __shfl(aa, q4*4+0), af1 = __shfl(aa, q4*4+1);
    float af2 = __shfl(aa, q4*4+2), af3 = __shfl(aa, q4*4+3);
    #pragma unroll
    for (int i = 0; i < 16; i++){
      O[i][0]*=af0; O[i][1]*=af1; O[i][2]*=af2; O[i][3]*=af3;
    }
    bf16x8 pa = *reinterpret_cast<const bf16x8*>(&Pbuf[wl][qrow][q4*8]);
    #pragma unroll
    for (int i = 0; i < 16; i++){
      const bf16_t* vp = Vlds + (size_t)(i*16 + qrow)*40 + q4*8;
      bf16x8 vb = *reinterpret_cast<const bf16x8*>(vp);
      O[i] = __builtin_amdgcn_mfma_f32_16x16x32_bf16(pa, vb, O[i], 0, 0, 0);
    }
  }

  __syncthreads();   // Vlds readers done; raw becomes ctxl
  {
    float lr0 = __shfl(l_, q4*4+0), lr1 = __shfl(l_, q4*4+1);
    float lr2 = __shfl(l_, q4*4+2), lr3 = __shfl(l_, q4*4+3);
    float i0 = lr0>0.f?1.f/lr0:0.f, i1 = lr1>0.f?1.f/lr1:0.f;
    float i2 = lr2>0.f?1.f/lr2:0.f, i3 = lr3>0.f?1.f/lr3:0.f;
    float* cw = ctxl + wl*4160;
    #pragma unroll
    for (int i = 0; i < 16; i++){
      cw[(q4*4+0)*260 + i*16+qrow] = O[i][0]*i0;
      cw[(q4*4+1)*260 + i*16+qrow] = O[i][1]*i1;
      cw[(q4*4+2)*260 + i*16+qrow] = O[i][2]*i2;
      cw[(q4*4+3)*260 + i*16+qrow] = O[i][3]*i3;
    }
  }
  const float* cw = ctxl + wl*4160;
  f32x4 Y[16];
  #pragma unroll
  for (int i = 0; i < 16; i++) Y[i] = (f32x4){0.f,0.f,0.f,0.f};
  #pragma unroll
  for (int s = 0; s < 8; s++){
    bf16x8 ca, cl;
    hilo8(cw + qrow*260 + s*32 + q4*8, ca, cl);
    #pragma unroll
    for (int tt = 0; tt < 16; tt++){
      const bf16_t* pb = PtT + (size_t)(tt*16 + qrow)*DIM + s*32 + q4*8;
      bf16x8 mb = *reinterpret_cast<const bf16x8*>(pb);
      Y[tt] = __builtin_amdgcn_mfma_f32_16x16x32_bf16(ca, mb, Y[tt], 0, 0, 0);
      Y[tt] = __builtin_amdgcn_mfma_f32_16x16x32_bf16(cl, mb, Y[tt], 0, 0, 0);
    }
  }
  float* YB = ctxl + wl*4160;
  #pragma unroll
  for (int tt = 0; tt < 16; tt++)
    #pragma unroll
    for (int r = 0; r < 4; r++)
      YB[(q4*4+r)*260 + tt*16 + qrow] = Y[tt][r];

  for (int i = 0; i < 16; i++){
    int grow = row0 + i;
    float4 yv = *reinterpret_cast<const float4*>(&YB[i*260 + 4*lane]);
    float4 xv = *reinterpret_cast<const float4*>(X  + (size_t)grow*DIM + 4*lane);
    float4 bv = *reinterpret_cast<const float4*>(bo + 4*lane);
    float4 gv = *reinterpret_cast<const float4*>(g  + 4*lane);
    float4 b2 = *reinterpret_cast<const float4*>(bb + 4*lane);
    float v0 = xv.x + yv.x + bv.x, v1 = xv.y + yv.y + bv.y;
    float v2 = xv.z + yv.z + bv.z, v3 = xv.w + yv.w + bv.w;
    float sum = wave_sum(v0+v1+v2+v3);
    float ssq = wave_sum(v0*v0+v1*v1+v2*v2+v3*v3);
    float mu  = sum * (1.0f/DIM);
    float var = ssq * (1.0f/DIM) - mu*mu;
    float rr  = rsqrtf(fmaxf(var, 0.f) + 1e-5f);
    float4 o;
    o.x = (v0-mu)*rr*gv.x + b2.x;
    o.y = (v1-mu)*rr*gv.y + b2.y;
    o.z = (v2-mu)*rr*gv.z + b2.z;
    o.w = (v3-mu)*rr*gv.w + b2.w;
    *reinterpret_cast<float4*>(out + (size_t)out_off + (size_t)grow*DIM + 4*lane) = o;
  }
}

extern "C" void kernel_launch(void* const* d_in, const int* in_sizes, int n_in,
                              void* d_out, int out_size, void* d_ws, size_t ws_size,
                              hipStream_t stream){
  const float* lig      = (const float*)d_in[0];
  const float* pro      = (const float*)d_in[1];
  const float* lig_pos  = (const float*)d_in[2];
  const float* pro_pos  = (const float*)d_in[3];
  const int*   lig_batch= (const int*)d_in[4];
  const int*   pro_batch= (const int*)d_in[5];
  const float* Wq_lig   = (const float*)d_in[6];
  const float* Wk_pro   = (const float*)d_in[7];
  const float* Wv_pro   = (const float*)d_in[8];
  const float* Wq_pro   = (const float*)d_in[9];
  const float* Wk_lig   = (const float*)d_in[10];
  const float* Wv_lig   = (const float*)d_in[11];
  const float* Wout_lig = (const float*)d_in[12];
  const float* bout_lig = (const float*)d_in[13];
  const float* Wout_pro = (const float*)d_in[14];
  const float* bout_pro = (const float*)d_in[15];
  const float* g_lig    = (const float*)d_in[16];
  const float* b_lig    = (const float*)d_in[17];
  const float* g_pro    = (const float*)d_in[18];
  const float* b_pro    = (const float*)d_in[19];

  // ws (~2.75 MB; proven safe): ints, 4 weight products, G, T_lig, mlpart
  int* ib        = (int*)d_ws;
  int* lig_start = ib + 16;
  int* pro_start = ib + 56;
  bf16_t* wsb  = ((bf16_t*)d_ws) + 256;
  bf16_t* A1   = wsb;                         // Wq_lig^T Wk_pro
  bf16_t* B2   = A1   + DIM*DIM;              // Wk_lig^T Wq_pro
  bf16_t* PtTL = B2   + DIM*DIM;              // Wout_lig @ Wv_pro  (= M_lig^T)
  bf16_t* PtTP = PtTL + DIM*DIM;              // Wout_pro @ Wv_lig  (= M_pro^T)
  bf16_t* G    = PtTP + DIM*DIM;              // lig @ B2   [2048][256]  (pro-side K)
  bf16_t* T_lig= G    + (size_t)NLr*DIM;      // lig @ A1   [2048][256]  (lig-side Q)
  float* mlpart= (float*)(T_lig + (size_t)NLr*DIM);   // 1024*32 floats

  float* outp = (float*)d_out;

  hipLaunchKernelGGL(bounds_kernel, dim3(1), dim3(64), 0, stream,
                     lig_batch, pro_batch, lig_start, pro_start);
  hipLaunchKernelGGL(wprod4, dim3(4,4,4), dim3(256), 0, stream,
                     Wq_lig, Wk_pro, Wk_lig, Wq_pro, Wout_lig, Wv_pro, Wout_pro, Wv_lig,
                     A1, B2, PtTL, PtTP);
  hipLaunchKernelGGL(gemm2, dim3(NLr/64, 4, 2), dim3(256), 0, stream,
                     lig, A1, B2, T_lig, G);

  // ligand <- protein: 128 tiles x 8 splits, partials, then merge
  hipLaunchKernelGGL(attn_lig, dim3(NLr/16*8), dim3(128), 0, stream,
                     T_lig, pro, lig_pos, pro_pos, lig_batch, pro_start, outp, mlpart, NPr);
  hipLaunchKernelGGL(merge_lig, dim3(NLr/16), dim3(128), 0, stream,
                     outp, mlpart, PtTL, lig, bout_lig, g_lig, b_lig, outp);

  // protein <- ligand (round-11 proven kernel; overwrites partial region after merge)
  hipLaunchKernelGGL(attn_pro, dim3(NPr/32), dim3(128), 0, stream,
                     pro, G, lig, pro_pos, lig_pos, pro_batch, lig_start, PtTP,
                     pro, bout_pro, g_pro, b_pro, outp, NLr*DIM, NLr);
}

// Round 14
// 246.996 us; speedup vs baseline: 1.1698x; 1.0649x over previous
//
#include <hip/hip_runtime.h>

static constexpr int NLr = 2048;    // ligand rows
static constexpr int NPr = 16384;   // protein rows
static constexpr int DIM = 256;     // feature dim
static constexpr int NB  = 32;      // batch count

typedef unsigned short bf16_t;
using bf16x8 = __attribute__((ext_vector_type(8))) short;
using f32x4  = __attribute__((ext_vector_type(4))) float;

__device__ inline float bf2f(bf16_t u){
  union { unsigned int i; float f; } c; c.i = ((unsigned int)u) << 16; return c.f;
}
__device__ inline bf16_t f2bf(float f){
  union { float f; unsigned int i; } c; c.f = f;
  unsigned int x = c.i;
  return (bf16_t)((x + 0x7fffu + ((x >> 16) & 1u)) >> 16);  // RNE
}
__device__ inline float wave_sum(float x){
  #pragma unroll
  for (int off = 32; off; off >>= 1) x += __shfl_xor(x, off, 64);
  return x;
}
// fp32 -> (hi, lo) bf16 pair
__device__ inline void hilo8(const float* p, bf16x8& hi, bf16x8& lo){
  #pragma unroll
  for (int i = 0; i < 8; i++){
    float v = p[i];
    bf16_t h = f2bf(v);
    hi[i] = (short)h;
    lo[i] = (short)f2bf(v - bf2f(h));
  }
}
__device__ inline int lbound(const int* __restrict__ a, int n, int v){
  int lo = 0, hi = n;
  while (lo < hi){ int mid = (lo + hi) >> 1; if (a[mid] < v) lo = mid + 1; else hi = mid; }
  return lo;
}

// d_out layout (floats): lig-out [0, 524288) | bf16 partials [524288, 2621440)
// | proB bf16 [2621440, 4718592). attn_pro overwrites [524288,...) afterwards.
static constexpr int OPART_OFF = 524288;    // float offset of bf16 partial region
static constexpr int PROB_OFF  = 2621440;   // float offset of proB

// ---- 4 weight products in one launch: z<2 -> A^T B ; z>=2 -> A B ----
__global__ __launch_bounds__(256) void wprod4(
    const float* __restrict__ Wq_lig, const float* __restrict__ Wk_pro,
    const float* __restrict__ Wk_lig, const float* __restrict__ Wq_pro,
    const float* __restrict__ Wout_lig, const float* __restrict__ Wv_pro,
    const float* __restrict__ Wout_pro, const float* __restrict__ Wv_lig,
    bf16_t* __restrict__ A1, bf16_t* __restrict__ B2,
    bf16_t* __restrict__ PtTL, bf16_t* __restrict__ PtTP){
  __shared__ float Sa[1088];
  __shared__ float Sb[1088];
  const int z = blockIdx.z;
  const float *A, *B; bf16_t* C;
  if      (z == 0){ A = Wq_lig;   B = Wk_pro; C = A1;   }
  else if (z == 1){ A = Wk_lig;   B = Wq_pro; C = B2;   }
  else if (z == 2){ A = Wout_lig; B = Wv_pro; C = PtTL; }
  else            { A = Wout_pro; B = Wv_lig; C = PtTP; }
  const int t  = threadIdx.x;
  const int tx = t & 15, ty = t >> 4;
  const int bm = blockIdx.x, bn = blockIdx.y;
  float acc[4][4] = {};
  if (z < 2){
    float (*As)[68] = (float(*)[68])Sa;
    float (*Bs)[68] = (float(*)[68])Sb;
    const int kk = t >> 4, c0 = (t & 15) << 2;
    for (int kt = 0; kt < DIM; kt += 16){
      float4 av = *reinterpret_cast<const float4*>(A + (size_t)(kt+kk)*DIM + bm*64 + c0);
      float4 bv = *reinterpret_cast<const float4*>(B + (size_t)(kt+kk)*DIM + bn*64 + c0);
      As[kk][c0+0]=av.x; As[kk][c0+1]=av.y; As[kk][c0+2]=av.z; As[kk][c0+3]=av.w;
      Bs[kk][c0+0]=bv.x; Bs[kk][c0+1]=bv.y; Bs[kk][c0+2]=bv.z; Bs[kk][c0+3]=bv.w;
      __syncthreads();
      #pragma unroll
      for (int k = 0; k < 16; k++){
        float a[4], b[4];
        #pragma unroll
        for (int i = 0; i < 4; i++) a[i] = As[k][ty*4+i];
        #pragma unroll
        for (int j = 0; j < 4; j++) b[j] = Bs[k][tx*4+j];
        #pragma unroll
        for (int i = 0; i < 4; i++)
          #pragma unroll
          for (int j = 0; j < 4; j++) acc[i][j] += a[i]*b[j];
      }
      __syncthreads();
    }
  } else {
    float (*As)[17] = (float(*)[17])Sa;
    float (*Bs)[68] = (float(*)[68])Sb;
    const int r  = t >> 2, k0 = (t & 3) << 2;
    const int kk = t >> 4, c0 = (t & 15) << 2;
    for (int kt = 0; kt < DIM; kt += 16){
      float4 av = *reinterpret_cast<const float4*>(A + (size_t)(bm*64+r)*DIM + kt + k0);
      float4 bv = *reinterpret_cast<const float4*>(B + (size_t)(kt+kk)*DIM + bn*64 + c0);
      As[r][k0+0]=av.x; As[r][k0+1]=av.y; As[r][k0+2]=av.z; As[r][k0+3]=av.w;
      Bs[kk][c0+0]=bv.x; Bs[kk][c0+1]=bv.y; Bs[kk][c0+2]=bv.z; Bs[kk][c0+3]=bv.w;
      __syncthreads();
      #pragma unroll
      for (int k = 0; k < 16; k++){
        float a[4], b[4];
        #pragma unroll
        for (int i = 0; i < 4; i++) a[i] = As[ty*4+i][k];
        #pragma unroll
        for (int j = 0; j < 4; j++) b[j] = Bs[k][tx*4+j];
        #pragma unroll
        for (int i = 0; i < 4; i++)
          #pragma unroll
          for (int j = 0; j < 4; j++) acc[i][j] += a[i]*b[j];
      }
      __syncthreads();
    }
  }
  #pragma unroll
  for (int i = 0; i < 4; i++){
    ushort4 o;
    o.x=f2bf(acc[i][0]); o.y=f2bf(acc[i][1]); o.z=f2bf(acc[i][2]); o.w=f2bf(acc[i][3]);
    *reinterpret_cast<ushort4*>(C + (size_t)(bm*64+ty*4+i)*DIM + bn*64 + tx*4) = o;
  }
}

// ---- two ligand projections + pro->bf16 cast in one launch (z: 0,1 gemm; 2 cast) ----
__global__ __launch_bounds__(256) void gemm2(
    const float* __restrict__ A, const bf16_t* __restrict__ Ba, const bf16_t* __restrict__ Bb,
    bf16_t* __restrict__ Ca, bf16_t* __restrict__ Cb,
    const float* __restrict__ pro, bf16_t* __restrict__ proB){
  if (blockIdx.z == 2){
    // cast: 128 blocks (32x4), grid-stride float4
    size_t base = ((size_t)(blockIdx.x*4 + blockIdx.y)*256 + threadIdx.x)*4;
    for (size_t i = base; i < (size_t)NPr*DIM; i += 131072){
      float4 v = *reinterpret_cast<const float4*>(pro + i);
      ushort4 o;
      o.x=f2bf(v.x); o.y=f2bf(v.y); o.z=f2bf(v.z); o.w=f2bf(v.w);
      *reinterpret_cast<ushort4*>(proB + i) = o;
    }
    return;
  }
  const bf16_t* B = blockIdx.z ? Bb : Ba;
  bf16_t*       C = blockIdx.z ? Cb : Ca;
  __shared__ float As[64][17];
  __shared__ float Bs[16][68];
  const int t  = threadIdx.x;
  const int r  = t >> 2, k0 = (t & 3) << 2;
  const int kk = t >> 4, c0 = (t & 15) << 2;
  const int tx = t & 15, ty = t >> 4;
  const int bm = blockIdx.x, bn = blockIdx.y;
  float acc[4][4] = {};
  for (int kt = 0; kt < DIM; kt += 16){
    float4 av = *reinterpret_cast<const float4*>(A + (size_t)(bm*64+r)*DIM + kt + k0);
    ushort4 bu = *reinterpret_cast<const ushort4*>(B + (size_t)(kt+kk)*DIM + bn*64 + c0);
    As[r][k0+0]=av.x; As[r][k0+1]=av.y; As[r][k0+2]=av.z; As[r][k0+3]=av.w;
    Bs[kk][c0+0]=bf2f(bu.x); Bs[kk][c0+1]=bf2f(bu.y);
    Bs[kk][c0+2]=bf2f(bu.z); Bs[kk][c0+3]=bf2f(bu.w);
    __syncthreads();
    #pragma unroll
    for (int k = 0; k < 16; k++){
      float a[4], b[4];
      #pragma unroll
      for (int i = 0; i < 4; i++) a[i] = As[ty*4+i][k];
      #pragma unroll
      for (int j = 0; j < 4; j++) b[j] = Bs[k][tx*4+j];
      #pragma unroll
      for (int i = 0; i < 4; i++)
        #pragma unroll
        for (int j = 0; j < 4; j++) acc[i][j] += a[i]*b[j];
    }
    __syncthreads();
  }
  #pragma unroll
  for (int i = 0; i < 4; i++){
    ushort4 o;
    o.x=f2bf(acc[i][0]); o.y=f2bf(acc[i][1]); o.z=f2bf(acc[i][2]); o.w=f2bf(acc[i][3]);
    *reinterpret_cast<ushort4*>(C + (size_t)(bm*64+ty*4+i)*DIM + bn*64 + tx*4) = o;
  }
}

// ==== ligand attention: 128 tiles x 8 key-splits = 1024 blocks; bf16 K/V + bf16 partials ====
__global__ __launch_bounds__(128) void attn_lig(
    const bf16_t* __restrict__ Qb, const bf16_t* __restrict__ Kb,
    const float* __restrict__ posA, const float* __restrict__ posB,
    const int* __restrict__ batchA, const int* __restrict__ pb,
    float* __restrict__ dout, float* __restrict__ mlpart){
  __shared__ __align__(16) char raw[36864];   // Vlds [256][72] bf16; later Ob [2][16][256] f32
  __shared__ bf16_t Pbuf[2][16][40];
  __shared__ float  mlb[2][2][16];
  bf16_t* Vlds = (bf16_t*)raw;
  float*  Ob   = (float*)raw;
  bf16_t* Opart = (bf16_t*)(dout + OPART_OFF);

  const int t = threadIdx.x, wl = t >> 6, lane = t & 63;
  const int qrow = lane & 15, q4 = lane >> 4;
  const int pidx = blockIdx.x, tile = pidx >> 3, split = pidx & 7;
  const int row0 = tile * 16;

  // inline bounds: per-row j0/j1, block kmin/kmax (rows block-uniform)
  const int rb = batchA[row0 + qrow];
  const int j0 = lbound(pb, NPr, rb);
  const int j1 = lbound(pb, NPr, rb + 1);
  const int kmin = __shfl(j0, 0);
  const int kmax = __shfl(j1, 15);
  const float ax = posA[(size_t)(row0+qrow)*3+0];
  const float ay = posA[(size_t)(row0+qrow)*3+1];
  const float az = posA[(size_t)(row0+qrow)*3+2];
  const int base = kmin & ~63;

  bf16x8 qf[8];
  #pragma unroll
  for (int s = 0; s < 8; s++)
    qf[s] = *reinterpret_cast<const bf16x8*>(Qb + (size_t)(row0+qrow)*DIM + s*32 + q4*8);

  f32x4 O[16];
  #pragma unroll
  for (int i = 0; i < 16; i++) O[i] = (f32x4){0.f,0.f,0.f,0.f};
  float m_ = -3.0e38f, l_ = 0.f;

  for (int c = base + split*64; c < kmax; c += 512){
    __syncthreads();
    {  // stage 64 keys x 256 dims bf16 -> transposed LDS, batched loads
      const int key = t & 63, half = t >> 6;
      const bf16_t* src = Kb + (size_t)min(c + key, NPr-1)*DIM + half*128;
      #pragma unroll
      for (int g = 0; g < 2; g++){
        bf16x8 tmp[8];
        #pragma unroll
        for (int u = 0; u < 8; u++)
          tmp[u] = *reinterpret_cast<const bf16x8*>(src + g*64 + u*8);
        #pragma unroll
        for (int u = 0; u < 8; u++){
          int d = half*128 + g*64 + u*8;
          #pragma unroll
          for (int jj = 0; jj < 8; jj++)
            Vlds[(d+jj)*72 + key] = (bf16_t)tmp[u][jj];
        }
      }
    }
    __syncthreads();

    const int kc0 = c + wl*32, colbase = wl*32;
    f32x4 a0 = (f32x4){0.f,0.f,0.f,0.f}, a1 = a0;
    const bf16_t* kr0 = Kb + (size_t)min(kc0 + qrow,      NPr-1)*DIM;
    const bf16_t* kr1 = Kb + (size_t)min(kc0 + 16 + qrow, NPr-1)*DIM;
    #pragma unroll
    for (int s = 0; s < 8; s++){
      bf16x8 ka = *reinterpret_cast<const bf16x8*>(kr0 + s*32 + q4*8);
      bf16x8 kb = *reinterpret_cast<const bf16x8*>(kr1 + s*32 + q4*8);
      a0 = __builtin_amdgcn_mfma_f32_16x16x32_bf16(ka, qf[s], a0, 0, 0, 0);
      a1 = __builtin_amdgcn_mfma_f32_16x16x32_bf16(kb, qf[s], a1, 0, 0, 0);
    }
    float sc[2][4]; bool vm[2][4];
    float cm = -3.0e38f;
    #pragma unroll
    for (int h = 0; h < 2; h++)
      #pragma unroll
      for (int r = 0; r < 4; r++){
        int key = kc0 + h*16 + q4*4 + r;
        bool vld = (key >= j0) && (key < j1);
        int kc = min(key, NPr-1);
        float bx = posB[(size_t)kc*3+0], by = posB[(size_t)kc*3+1], bz = posB[(size_t)kc*3+2];
        float dx = ax-bx, dy = ay-by, dz = az-bz;
        float dist = sqrtf(fmaxf(dx*dx + dy*dy + dz*dz, 1e-12f));
        float sv = (h ? a1[r] : a0[r]) * 0.0625f + __expf(-0.1f*dist);
        sc[h][r] = vld ? sv : -3.0e38f;
        vm[h][r] = vld;
        cm = fmaxf(cm, sc[h][r]);
      }
    cm = fmaxf(cm, __shfl_xor(cm, 16));
    cm = fmaxf(cm, __shfl_xor(cm, 32));
    float mn = fmaxf(m_, cm);
    float aa = __expf(m_ - mn);
    float p[2][4]; float ps = 0.f;
    #pragma unroll
    for (int h = 0; h < 2; h++)
      #pragma unroll
      for (int r = 0; r < 4; r++){
        p[h][r] = vm[h][r] ? __expf(sc[h][r] - mn) : 0.f;
        ps += p[h][r];
      }
    ps += __shfl_xor(ps, 16);
    ps += __shfl_xor(ps, 32);
    l_ = l_*aa + ps;
    m_ = mn;
    ushort4 w0, w1;
    w0.x=f2bf(p[0][0]); w0.y=f2bf(p[0][1]); w0.z=f2bf(p[0][2]); w0.w=f2bf(p[0][3]);
    w1.x=f2bf(p[1][0]); w1.y=f2bf(p[1][1]); w1.z=f2bf(p[1][2]); w1.w=f2bf(p[1][3]);
    *reinterpret_cast<ushort4*>(&Pbuf[wl][qrow][q4*4])      = w0;
    *reinterpret_cast<ushort4*>(&Pbuf[wl][qrow][16 + q4*4]) = w1;
    float af0 = __shfl(aa, q4*4+0), af1 = __shfl(aa, q4*4+1);
    float af2 = __shfl(aa, q4*4+2), af3 = __shfl(aa, q4*4+3);
    #pragma unroll
    for (int i = 0; i < 16; i++){
      O[i][0]*=af0; O[i][1]*=af1; O[i][2]*=af2; O[i][3]*=af3;
    }
    bf16x8 pa = *reinterpret_cast<const bf16x8*>(&Pbuf[wl][qrow][q4*8]);
    #pragma unroll
    for (int i = 0; i < 16; i++){
      const bf16_t* vp = Vlds + (size_t)(i*16 + qrow)*72 + colbase + q4*8;
      bf16x8 vb = *reinterpret_cast<const bf16x8*>(vp);
      O[i] = __builtin_amdgcn_mfma_f32_16x16x32_bf16(pa, vb, O[i], 0, 0, 0);
    }
  }

  // in-block 2-wave merge (un-normalized) -> write bf16 partial
  __syncthreads();
  if (lane < 16){ mlb[wl][0][lane] = m_; mlb[wl][1][lane] = l_; }
  #pragma unroll
  for (int i = 0; i < 16; i++)
    #pragma unroll
    for (int r = 0; r < 4; r++)
      Ob[wl*4096 + (q4*4+r)*256 + i*16 + qrow] = O[i][r];
  __syncthreads();
  for (int e = t; e < 4096; e += 128){
    int row = e >> 8;
    float m0 = mlb[0][0][row], m1 = mlb[1][0][row];
    float mg = fmaxf(m0, m1);
    float f0 = __expf(m0 - mg), f1 = __expf(m1 - mg);
    Opart[(size_t)pidx*4096 + e] = f2bf(Ob[e]*f0 + Ob[4096 + e]*f1);
  }
  if (t < 16){
    float m0 = mlb[0][0][t], l0 = mlb[0][1][t];
    float m1 = mlb[1][0][t], l1 = mlb[1][1][t];
    float mg = fmaxf(m0, m1);
    mlpart[pidx*32 + t]      = mg;
    mlpart[pidx*32 + 16 + t] = l0*__expf(m0-mg) + l1*__expf(m1-mg);
  }
}

// ==== ligand merge (8 bf16 partials) + out-projection + residual + LN ====
__global__ __launch_bounds__(128) void merge_lig(
    const float* __restrict__ dpart, const float* __restrict__ mlpart,
    const bf16_t* __restrict__ PtT,
    const float* __restrict__ X, const float* __restrict__ bo,
    const float* __restrict__ g, const float* __restrict__ bb,
    float* __restrict__ out){
  __shared__ float ctxl[16*260];
  __shared__ float Yb[16*260];
  __shared__ float wgt[8][16];
  __shared__ float dens[16];
  const bf16_t* Opart = (const bf16_t*)(dpart + OPART_OFF);
  const int t = threadIdx.x, wl = t >> 6, lane = t & 63;
  const int qrow = lane & 15, q4 = lane >> 4;
  const int tile = blockIdx.x, row0 = tile*16;
  if (t < 16){
    float mm[8], ll[8], mg = -3.0e38f;
    #pragma unroll
    for (int s = 0; s < 8; s++){
      mm[s] = mlpart[(tile*8+s)*32 + t];
      ll[s] = mlpart[(tile*8+s)*32 + 16 + t];
      mg = fmaxf(mg, mm[s]);
    }
    float den = 0.f;
    #pragma unroll
    for (int s = 0; s < 8; s++){
      float w = __expf(mm[s] - mg);
      wgt[s][t] = w;
      den += ll[s]*w;
    }
    dens[t] = den;
  }
  __syncthreads();
  for (int e = t; e < 4096; e += 128){
    int row = e >> 8, d = e & 255;
    float acc = 0.f;
    #pragma unroll
    for (int s = 0; s < 8; s++)
      acc += bf2f(Opart[((size_t)(tile*8+s))*4096 + e]) * wgt[s][row];
    float dd = dens[row];
    ctxl[row*260 + d] = (dd > 0.f) ? acc/dd : 0.f;
  }
  __syncthreads();
  f32x4 Y[8];
  #pragma unroll
  for (int i = 0; i < 8; i++) Y[i] = (f32x4){0.f,0.f,0.f,0.f};
  #pragma unroll
  for (int s = 0; s < 8; s++){
    bf16x8 ca, cl;
    hilo8(ctxl + qrow*260 + s*32 + q4*8, ca, cl);
    #pragma unroll
    for (int tt = 0; tt < 8; tt++){
      const bf16_t* pb = PtT + (size_t)((wl*8+tt)*16 + qrow)*DIM + s*32 + q4*8;
      bf16x8 mb = *reinterpret_cast<const bf16x8*>(pb);
      Y[tt] = __builtin_amdgcn_mfma_f32_16x16x32_bf16(ca, mb, Y[tt], 0, 0, 0);
      Y[tt] = __builtin_amdgcn_mfma_f32_16x16x32_bf16(cl, mb, Y[tt], 0, 0, 0);
    }
  }
  #pragma unroll
  for (int tt = 0; tt < 8; tt++)
    #pragma unroll
    for (int r = 0; r < 4; r++)
      Yb[(q4*4+r)*260 + (wl*8+tt)*16 + qrow] = Y[tt][r];
  __syncthreads();
  for (int i = 0; i < 8; i++){
    int r = wl*8 + i, grow = row0 + r;
    float4 yv = *reinterpret_cast<const float4*>(&Yb[r*260 + 4*lane]);
    float4 xv = *reinterpret_cast<const float4*>(X  + (size_t)grow*DIM + 4*lane);
    float4 bv = *reinterpret_cast<const float4*>(bo + 4*lane);
    float4 gv = *reinterpret_cast<const float4*>(g  + 4*lane);
    float4 b2 = *reinterpret_cast<const float4*>(bb + 4*lane);
    float v0 = xv.x + yv.x + bv.x, v1 = xv.y + yv.y + bv.y;
    float v2 = xv.z + yv.z + bv.z, v3 = xv.w + yv.w + bv.w;
    float sum = wave_sum(v0+v1+v2+v3);
    float ssq = wave_sum(v0*v0+v1*v1+v2*v2+v3*v3);
    float mu  = sum * (1.0f/DIM);
    float var = ssq * (1.0f/DIM) - mu*mu;
    float rr  = rsqrtf(fmaxf(var, 0.f) + 1e-5f);
    float4 o;
    o.x = (v0-mu)*rr*gv.x + b2.x;
    o.y = (v1-mu)*rr*gv.y + b2.y;
    o.z = (v2-mu)*rr*gv.z + b2.z;
    o.w = (v3-mu)*rr*gv.w + b2.w;
    *reinterpret_cast<float4*>(out + (size_t)grow*DIM + 4*lane) = o;
  }
}

// ==== protein attention (round-11 proven version, bounds inlined) ====
__global__ __launch_bounds__(128) void attn_pro(
    const float* __restrict__ Qf, const bf16_t* __restrict__ Kb,
    const float* __restrict__ Vf,
    const float* __restrict__ posA, const float* __restrict__ posB,
    const int* __restrict__ batchA, const int* __restrict__ lb,
    const bf16_t* __restrict__ PtT,
    const float* __restrict__ X, const float* __restrict__ bo,
    const float* __restrict__ g, const float* __restrict__ bb,
    float* __restrict__ out, int out_off){
  __shared__ __align__(16) char raw[33280];  // Vlds [256][40] bf16; later ctxl [2][16][260] f32
  __shared__ bf16_t Pbuf[2][16][40];
  bf16_t* Vlds = (bf16_t*)raw;
  float*  ctxl = (float*)raw;

  const int t = threadIdx.x, wl = t >> 6, lane = t & 63;
  const int qrow = lane & 15, q4 = lane >> 4;
  const int row0b = blockIdx.x * 32, row0 = row0b + wl*16;

  // inline bounds
  const int rb = batchA[row0 + qrow];
  const int j0 = lbound(lb, NLr, rb);
  const int j1 = lbound(lb, NLr, rb + 1);
  const int bfirst = batchA[row0b];
  const int blast  = batchA[row0b + 31];
  const int kmin = lbound(lb, NLr, bfirst);
  const int kmax = lbound(lb, NLr, blast + 1);
  const float ax = posA[(size_t)(row0+qrow)*3+0];
  const float ay = posA[(size_t)(row0+qrow)*3+1];
  const float az = posA[(size_t)(row0+qrow)*3+2];
  const int base = kmin & ~31;

  bf16x8 qf[8], ql[8];
  #pragma unroll
  for (int s = 0; s < 8; s++)
    hilo8(Qf + (size_t)(row0+qrow)*DIM + s*32 + q4*8, qf[s], ql[s]);

  f32x4 O[16];
  #pragma unroll
  for (int i = 0; i < 16; i++) O[i] = (f32x4){0.f,0.f,0.f,0.f};
  float m_ = -3.0e38f, l_ = 0.f;

  for (int c = base; c < kmax; c += 32){
    __syncthreads();
    {  // stage 32 keys x 256 dims from fp32, batched
      const int key = t & 31, qtr = t >> 5;
      const float* src = Vf + (size_t)min(c + key, NLr-1)*DIM + qtr*64;
      #pragma unroll
      for (int gch = 0; gch < 2; gch++){
        float4 tmp[8];
        #pragma unroll
        for (int u = 0; u < 8; u++)
          tmp[u] = *reinterpret_cast<const float4*>(src + gch*32 + u*4);
        #pragma unroll
        for (int u = 0; u < 8; u++){
          int d = qtr*64 + gch*32 + u*4;
          Vlds[(d+0)*40 + key] = f2bf(tmp[u].x);
          Vlds[(d+1)*40 + key] = f2bf(tmp[u].y);
          Vlds[(d+2)*40 + key] = f2bf(tmp[u].z);
          Vlds[(d+3)*40 + key] = f2bf(tmp[u].w);
        }
      }
    }
    __syncthreads();

    f32x4 a0 = (f32x4){0.f,0.f,0.f,0.f}, a1 = a0;
    const bf16_t* kr0 = Kb + (size_t)min(c + qrow,      NLr-1)*DIM;
    const bf16_t* kr1 = Kb + (size_t)min(c + 16 + qrow, NLr-1)*DIM;
    #pragma unroll
    for (int s = 0; s < 8; s++){
      bf16x8 ka = *reinterpret_cast<const bf16x8*>(kr0 + s*32 + q4*8);
      bf16x8 kb = *reinterpret_cast<const bf16x8*>(kr1 + s*32 + q4*8);
      a0 = __builtin_amdgcn_mfma_f32_16x16x32_bf16(ka, qf[s], a0, 0, 0, 0);
      a1 = __builtin_amdgcn_mfma_f32_16x16x32_bf16(kb, qf[s], a1, 0, 0, 0);
      a0 = __builtin_amdgcn_mfma_f32_16x16x32_bf16(ka, ql[s], a0, 0, 0, 0);
      a1 = __builtin_amdgcn_mfma_f32_16x16x32_bf16(kb, ql[s], a1, 0, 0, 0);
    }
    float sc[2][4]; bool vm[2][4];
    float cm = -3.0e38f;
    #pragma unroll
    for (int h = 0; h < 2; h++)
      #pragma unroll
      for (int r = 0; r < 4; r++){
        int key = c + h*16 + q4*4 + r;
        bool vld = (key >= j0) && (key < j1);
        int kc = min(key, NLr-1);
        float bx = posB[(size_t)kc*3+0], by = posB[(size_t)kc*3+1], bz = posB[(size_t)kc*3+2];
        float dx = ax-bx, dy = ay-by, dz = az-bz;
        float dist = sqrtf(fmaxf(dx*dx + dy*dy + dz*dz, 1e-12f));
        float sv = (h ? a1[r] : a0[r]) * 0.0625f + __expf(-0.1f*dist);
        sc[h][r] = vld ? sv : -3.0e38f;
        vm[h][r] = vld;
        cm = fmaxf(cm, sc[h][r]);
      }
    cm = fmaxf(cm, __shfl_xor(cm, 16));
    cm = fmaxf(cm, __shfl_xor(cm, 32));
    float mn = fmaxf(m_, cm);
    float aa = __expf(m_ - mn);
    float p[2][4]; float ps = 0.f;
    #pragma unroll
    for (int h = 0; h < 2; h++)
      #pragma unroll
      for (int r = 0; r < 4; r++){
        p[h][r] = vm[h][r] ? __expf(sc[h][r] - mn) : 0.f;
        ps += p[h][r];
      }
    ps += __shfl_xor(ps, 16);
    ps += __shfl_xor(ps, 32);
    l_ = l_*aa + ps;
    m_ = mn;
    ushort4 w0, w1;
    w0.x=f2bf(p[0][0]); w0.y=f2bf(p[0][1]); w0.z=f2bf(p[0][2]); w0.w=f2bf(p[0][3]);
    w1.x=f2bf(p[1][0]); w1.y=f2bf(p[1][1]); w1.z=f2bf(p[1][2]); w1.w=f2bf(p[1][3]);
    *reinterpret_cast<ushort4*>(&Pbuf[wl][qrow][q4*4])      = w0;
    *reinterpret_cast<ushort4*>(&Pbuf[wl][qrow][16 + q4*4]) = w1;
    float af0 = __shfl(aa, q4*4+0), af1 = __shfl(aa, q4*4+1);
    float af2 = __shfl(aa, q4*4+2), af3 = __shfl(aa, q4*4+3);
    #pragma unroll
    for (int i = 0; i < 16; i++){
      O[i][0]*=af0; O[i][1]*=af1; O[i][2]*=af2; O[i][3]*=af3;
    }
    bf16x8 pa = *reinterpret_cast<const bf16x8*>(&Pbuf[wl][qrow][q4*8]);
    #pragma unroll
    for (int i = 0; i < 16; i++){
      const bf16_t* vp = Vlds + (size_t)(i*16 + qrow)*40 + q4*8;
      bf16x8 vb = *reinterpret_cast<const bf16x8*>(vp);
      O[i] = __builtin_amdgcn_mfma_f32_16x16x32_bf16(pa, vb, O[i], 0, 0, 0);
    }
  }

  __syncthreads();   // Vlds readers done; raw becomes ctxl
  {
    float lr0 = __shfl(l_, q4*4+0), lr1 = __shfl(l_, q4*4+1);
    float lr2 = __shfl(l_, q4*4+2), lr3 = __shfl(l_, q4*4+3);
    float i0 = lr0>0.f?1.f/lr0:0.f, i1 = lr1>0.f?1.f/lr1:0.f;
    float i2 = lr2>0.f?1.f/lr2:0.f, i3 = lr3>0.f?1.f/lr3:0.f;
    float* cw = ctxl + wl*4160;
    #pragma unroll
    for (int i = 0; i < 16; i++){
      cw[(q4*4+0)*260 + i*16+qrow] = O[i][0]*i0;
      cw[(q4*4+1)*260 + i*16+qrow] = O[i][1]*i1;
      cw[(q4*4+2)*260 + i*16+qrow] = O[i][2]*i2;
      cw[(q4*4+3)*260 + i*16+qrow] = O[i][3]*i3;
    }
  }
  const float* cw = ctxl + wl*4160;
  f32x4 Y[16];
  #pragma unroll
  for (int i = 0; i < 16; i++) Y[i] = (f32x4){0.f,0.f,0.f,0.f};
  #pragma unroll
  for (int s = 0; s < 8; s++){
    bf16x8 ca, cl;
    hilo8(cw + qrow*260 + s*32 + q4*8, ca, cl);
    #pragma unroll
    for (int tt = 0; tt < 16; tt++){
      const bf16_t* pb = PtT + (size_t)(tt*16 + qrow)*DIM + s*32 + q4*8;
      bf16x8 mb = *reinterpret_cast<const bf16x8*>(pb);
      Y[tt] = __builtin_amdgcn_mfma_f32_16x16x32_bf16(ca, mb, Y[tt], 0, 0, 0);
      Y[tt] = __builtin_amdgcn_mfma_f32_16x16x32_bf16(cl, mb, Y[tt], 0, 0, 0);
    }
  }
  float* YB = ctxl + wl*4160;
  #pragma unroll
  for (int tt = 0; tt < 16; tt++)
    #pragma unroll
    for (int r = 0; r < 4; r++)
      YB[(q4*4+r)*260 + tt*16 + qrow] = Y[tt][r];

  for (int i = 0; i < 16; i++){
    int grow = row0 + i;
    float4 yv = *reinterpret_cast<const float4*>(&YB[i*260 + 4*lane]);
    float4 xv = *reinterpret_cast<const float4*>(X  + (size_t)grow*DIM + 4*lane);
    float4 bv = *reinterpret_cast<const float4*>(bo + 4*lane);
    float4 gv = *reinterpret_cast<const float4*>(g  + 4*lane);
    float4 b2 = *reinterpret_cast<const float4*>(bb + 4*lane);
    float v0 = xv.x + yv.x + bv.x, v1 = xv.y + yv.y + bv.y;
    float v2 = xv.z + yv.z + bv.z, v3 = xv.w + yv.w + bv.w;
    float sum = wave_sum(v0+v1+v2+v3);
    float ssq = wave_sum(v0*v0+v1*v1+v2*v2+v3*v3);
    float mu  = sum * (1.0f/DIM);
    float var = ssq * (1.0f/DIM) - mu*mu;
    float rr  = rsqrtf(fmaxf(var, 0.f) + 1e-5f);
    float4 o;
    o.x = (v0-mu)*rr*gv.x + b2.x;
    o.y = (v1-mu)*rr*gv.y + b2.y;
    o.z = (v2-mu)*rr*gv.z + b2.z;
    o.w = (v3-mu)*rr*gv.w + b2.w;
    *reinterpret_cast<float4*>(out + (size_t)out_off + (size_t)grow*DIM + 4*lane) = o;
  }
}

extern "C" void kernel_launch(void* const* d_in, const int* in_sizes, int n_in,
                              void* d_out, int out_size, void* d_ws, size_t ws_size,
                              hipStream_t stream){
  const float* lig      = (const float*)d_in[0];
  const float* pro      = (const float*)d_in[1];
  const float* lig_pos  = (const float*)d_in[2];
  const float* pro_pos  = (const float*)d_in[3];
  const int*   lig_batch= (const int*)d_in[4];
  const int*   pro_batch= (const int*)d_in[5];
  const float* Wq_lig   = (const float*)d_in[6];
  const float* Wk_pro   = (const float*)d_in[7];
  const float* Wv_pro   = (const float*)d_in[8];
  const float* Wq_pro   = (const float*)d_in[9];
  const float* Wk_lig   = (const float*)d_in[10];
  const float* Wv_lig   = (const float*)d_in[11];
  const float* Wout_lig = (const float*)d_in[12];
  const float* bout_lig = (const float*)d_in[13];
  const float* Wout_pro = (const float*)d_in[14];
  const float* bout_pro = (const float*)d_in[15];
  const float* g_lig    = (const float*)d_in[16];
  const float* b_lig    = (const float*)d_in[17];
  const float* g_pro    = (const float*)d_in[18];
  const float* b_pro    = (const float*)d_in[19];

  // ws (~2.75 MB; proven safe): 4 weight products, G, T_lig, mlpart
  bf16_t* wsb  = ((bf16_t*)d_ws) + 256;
  bf16_t* A1   = wsb;                         // Wq_lig^T Wk_pro
  bf16_t* B2   = A1   + DIM*DIM;              // Wk_lig^T Wq_pro
  bf16_t* PtTL = B2   + DIM*DIM;              // Wout_lig @ Wv_pro  (= M_lig^T)
  bf16_t* PtTP = PtTL + DIM*DIM;              // Wout_pro @ Wv_lig  (= M_pro^T)
  bf16_t* G    = PtTP + DIM*DIM;              // lig @ B2   [2048][256]  (pro-side K)
  bf16_t* T_lig= G    + (size_t)NLr*DIM;      // lig @ A1   [2048][256]  (lig-side Q)
  float* mlpart= (float*)(T_lig + (size_t)NLr*DIM);   // 1024*32 floats

  float* outp = (float*)d_out;
  bf16_t* proB = (bf16_t*)(outp + PROB_OFF);  // bf16(pro) [16384][256] in d_out tail

  hipLaunchKernelGGL(wprod4, dim3(4,4,4), dim3(256), 0, stream,
                     Wq_lig, Wk_pro, Wk_lig, Wq_pro, Wout_lig, Wv_pro, Wout_pro, Wv_lig,
                     A1, B2, PtTL, PtTP);
  hipLaunchKernelGGL(gemm2, dim3(NLr/64, 4, 3), dim3(256), 0, stream,
                     lig, A1, B2, T_lig, G, pro, proB);

  // ligand <- protein: 128 tiles x 8 splits, bf16 partials, then merge
  hipLaunchKernelGGL(attn_lig, dim3(NLr/16*8), dim3(128), 0, stream,
                     T_lig, proB, lig_pos, pro_pos, lig_batch, pro_batch, outp, mlpart);
  hipLaunchKernelGGL(merge_lig, dim3(NLr/16), dim3(128), 0, stream,
                     outp, mlpart, PtTL, lig, bout_lig, g_lig, b_lig, outp);

  // protein <- ligand (overwrites partials+proB only after merge consumed them)
  hipLaunchKernelGGL(attn_pro, dim3(NPr/32), dim3(128), 0, stream,
                     pro, G, lig, pro_pos, lig_pos, pro_batch, lig_batch, PtTP,
                     pro, bout_pro, g_pro, b_pro, outp, NLr*DIM);
}